// Round 14
// baseline (625.040 us; speedup 1.0000x reference)
//
#include <hip/hip_runtime.h>
#include <hip/hip_bf16.h>
#include <stdint.h>

#define DEVI __device__ __forceinline__

typedef unsigned short u16;
typedef __attribute__((ext_vector_type(8))) short short8;
typedef __attribute__((ext_vector_type(4))) float f32x4;
typedef __attribute__((ext_vector_type(16))) float f32x16;

DEVI u16 f2bf(float f) {
  union { float f; uint32_t u; } v; v.f = f;
  return (u16)((v.u + 0x7fffu + ((v.u >> 16) & 1u)) >> 16);
}
DEVI float tanh_c(float x) {
  float e = __expf(x + x);
  float r = __builtin_amdgcn_rcpf(e + 1.0f);
  return __builtin_fmaf(-2.0f, r, 1.0f);
}
DEVI float sigm(float x) { return __builtin_amdgcn_rcpf(1.0f + __expf(-x)); }
DEVI uint32_t tj2(float a, float b) {
  float ea = __expf(a + a), eb = __expf(b + b);
  float ta = __builtin_fmaf(-2.0f, __builtin_amdgcn_rcpf(ea + 1.0f), 1.0f);
  float tb = __builtin_fmaf(-2.0f, __builtin_amdgcn_rcpf(eb + 1.0f), 1.0f);
  union { __hip_bfloat162 h; uint32_t u; } cv;
  cv.h = __float22bfloat162_rn(make_float2(ta, tb));
  return cv.u;
}
DEVI short8 ald16(const u16* p) {
  union { unsigned long long q[2]; short8 v; } u;
  u.q[0] = __hip_atomic_load((unsigned long long*)p,       __ATOMIC_RELAXED, __HIP_MEMORY_SCOPE_AGENT);
  u.q[1] = __hip_atomic_load((unsigned long long*)(p + 4), __ATOMIC_RELAXED, __HIP_MEMORY_SCOPE_AGENT);
  return u.v;
}

// ---------------------------------------------------------------- prep
__global__ void prep_kernel(
    const float* __restrict__ W_ih0, const float* __restrict__ W_hh0,
    const float* __restrict__ W_ih1, const float* __restrict__ W_hh1,
    const float* __restrict__ W_enc, const float* __restrict__ W_dec,
    const float* __restrict__ W_out, const float* __restrict__ embed,
    const float* __restrict__ hs_pad,
    const float* __restrict__ b_ih0, const float* __restrict__ b_hh0,
    const float* __restrict__ b_ih1, const float* __restrict__ b_hh1,
    const float* __restrict__ b_out,
    u16* __restrict__ Wih0b, u16* __restrict__ Whh0b,
    u16* __restrict__ Wih1b, u16* __restrict__ Whh1b,
    u16* __restrict__ Wencb, u16* __restrict__ Wdecb,
    u16* __restrict__ embedb, u16* __restrict__ hsb,
    u16* __restrict__ Wshufb,
    float* __restrict__ bsum0, float* __restrict__ bsum1, float* __restrict__ boutp)
{
  const int c1 = 1048576, c2 = 2097152, c3 = 3145728, c4 = 4194304;
  const int c5 = 4456448, c6 = 4718592, c7 = 5025792, c8 = 6664192;
  const int c9 = 6991872, c10 = 6993920, c11 = 6995968, c12 = 6996608;
  for (int i = blockIdx.x * blockDim.x + threadIdx.x; i < c12; i += gridDim.x * blockDim.x) {
    if (i < c1)       Wih0b[i]      = f2bf(W_ih0[i]);
    else if (i < c2)  Whh0b[i - c1] = f2bf(W_hh0[i - c1]);
    else if (i < c3)  Wih1b[i - c2] = f2bf(W_ih1[i - c2]);
    else if (i < c4)  Whh1b[i - c3] = f2bf(W_hh1[i - c3]);
    else if (i < c5)  Wencb[i - c4] = f2bf(W_enc[i - c4]);
    else if (i < c6)  Wdecb[i - c5] = f2bf(W_dec[i - c5]);
    else if (i < c7)  embedb[i - c6] = f2bf(embed[i - c6]);
    else if (i < c8)  hsb[i - c7]   = f2bf(hs_pad[i - c7]);
    else if (i < c9) {
      int e = i - c8;
      int kc = e / 10240, r = e % 10240;
      int tile = r >> 9, r2 = r & 511;
      int lane = r2 >> 3, ii = r2 & 7;
      int n = tile * 32 + (lane & 31);
      int k = kc * 16 + ((lane >> 5) << 3) + ii;
      Wshufb[e] = (n < 600) ? f2bf(W_out[n * 512 + k]) : (u16)0;
    }
    else if (i < c10) { int n = i - c9;  bsum0[n] = b_ih0[n] + b_hh0[n]; }
    else if (i < c11) { int n = i - c10; bsum1[n] = b_ih1[n] + b_hh1[n]; }
    else              { int n = i - c11; boutp[n] = (n < 600) ? b_out[n] : 0.0f; }
  }
}

// ---------------------------------------------- 64x64 MFMA GEMM tile (device)
// MODE 1: A-row = A[ys[b*64+u]], m = u*16+b. AAT: coherent A loads. SAT: coherent stores.
template<int MODE, bool AAT, bool SAT>
DEVI void gemm_tile(const u16* __restrict__ A, const u16* __restrict__ B,
                    const int* __restrict__ ys, const float* __restrict__ bias,
                    float* __restrict__ out, int N, int m0, int n0, int tid)
{
  int wv = tid >> 6, l = tid & 63;
  int row = m0 + wv * 16 + (l & 15);
  const u16* arow;
  if (MODE == 1) { int uu = row >> 4, bb = row & 15; arow = A + (size_t)ys[bb * 64 + uu] * 512; }
  else           arow = A + (size_t)row * 512;
  int kof = (l >> 4) * 8;
  arow += kof;
  const u16* br = B + (size_t)(n0 + (l & 15)) * 512 + kof;
  f32x4 a0 = {0.f,0.f,0.f,0.f}, a1 = a0, a2 = a0, a3 = a0;
  for (int kk = 0; kk < 512; kk += 32) {
    short8 av = AAT ? ald16(arow + kk) : *(const short8*)(arow + kk);
    short8 b0 = *(const short8*)(br + kk);
    short8 b1 = *(const short8*)(br + 8192 + kk);
    short8 b2 = *(const short8*)(br + 16384 + kk);
    short8 b3 = *(const short8*)(br + 24576 + kk);
    a0 = __builtin_amdgcn_mfma_f32_16x16x32_bf16(av, b0, a0, 0, 0, 0);
    a1 = __builtin_amdgcn_mfma_f32_16x16x32_bf16(av, b1, a1, 0, 0, 0);
    a2 = __builtin_amdgcn_mfma_f32_16x16x32_bf16(av, b2, a2, 0, 0, 0);
    a3 = __builtin_amdgcn_mfma_f32_16x16x32_bf16(av, b3, a3, 0, 0, 0);
  }
  int col = l & 15, rb = m0 + wv * 16 + (l >> 4) * 4;
  f32x4 accs[4] = {a0, a1, a2, a3};
#pragma unroll
  for (int g = 0; g < 4; ++g) {
    int n = n0 + g * 16 + col;
    float bs = bias ? bias[n] : 0.0f;
#pragma unroll
    for (int i2 = 0; i2 < 4; ++i2) {
      float v = accs[g][i2] + bs;
      if (SAT)
        __hip_atomic_store(&out[(size_t)(rb + i2) * N + n], v,
                           __ATOMIC_RELAXED, __HIP_MEMORY_SCOPE_AGENT);
      else
        out[(size_t)(rb + i2) * N + n] = v;
    }
  }
}

// ---------------------------------------------------------------- fused LSTM
// bid 0..95: LSTM (L0: 0-31 / L1: 32-95), r11 flag protocol.
// bid 96..607: Xg0 GEMM (mode1, coherent stores) + xcnt readiness counters.
// bid 608..1007: enc_p GEMM (independent).
// bid 1008..1135: dec_p GEMM (waits flags1, coherent Hdec loads).
// Deadlock-safe: blockers (96+128) << resident capacity; 912 WGs never wait.
#define L0WG 32
#define FUSED_WG 1136

DEVI void waitflags(const int* f0, const int* f1, const int* xc, int n0, int n1, int xneed) {
  if (threadIdx.x < 64) {
    int l = threadIdx.x;
    for (;;) {
      int a = __hip_atomic_load((int*)(f0 + (l & 31) * 16), __ATOMIC_RELAXED, __HIP_MEMORY_SCOPE_AGENT);
      int b = __hip_atomic_load((int*)(f1 + l * 16),        __ATOMIC_RELAXED, __HIP_MEMORY_SCOPE_AGENT);
      int c = xc ? __hip_atomic_load((int*)xc, __ATOMIC_RELAXED, __HIP_MEMORY_SCOPE_AGENT) : xneed;
      if (__all(a >= n0 && b >= n1 && c >= xneed)) break;
      __builtin_amdgcn_s_sleep(1);
    }
    __builtin_amdgcn_fence(__ATOMIC_ACQUIRE, "agent");
  }
  __syncthreads();
}
DEVI void postflag(int* slot, int val) {
  __syncthreads();   // barrier drains each wave's vmcnt -> h stores at L3
  if (threadIdx.x == 0)
    __hip_atomic_store(slot, val, __ATOMIC_RELAXED, __HIP_MEMORY_SCOPE_AGENT);
}
DEVI const u16* haddr(const u16* base, int slot, int k, int b) {
  return base + slot * 8192 + (k >> 4) * 256 + b * 16 + (k & 15);
}
DEVI void hstore(u16* base, int idx, u16 mine, int tid) {
  int other = __shfl_xor((int)mine, 1);
  if (!(tid & 1)) {
    uint32_t pkv = (uint32_t)mine | (((uint32_t)other & 0xffffu) << 16);
    __hip_atomic_store((uint32_t*)(base + idx), pkv, __ATOMIC_RELAXED, __HIP_MEMORY_SCOPE_AGENT);
  }
}

__global__ __launch_bounds__(256) void lstm_fused(
    const u16* __restrict__ embedb, const u16* __restrict__ Wih0b,
    const int* __restrict__ ys, const float* __restrict__ bsum0,
    float* __restrict__ Xg0,                       // [64][16][2048]
    const u16* __restrict__ hsb, const u16* __restrict__ Wencb,
    const float* __restrict__ b_enc, float* __restrict__ enc_p,
    const u16* __restrict__ Wdecb, float* __restrict__ dec_p,
    const u16* __restrict__ Whh0, const u16* __restrict__ Wih1, const u16* __restrict__ Whh1,
    const float* __restrict__ bsum1,
    u16* __restrict__ h0b, u16* __restrict__ h1b,  // [8][32][16][16] rings
    u16* __restrict__ Hdec,                        // [64][16][512] bf16 (coherent)
    int* __restrict__ flags0, int* __restrict__ flags1, int* __restrict__ xcnt)
{
  __shared__ float red[16][256];
  const int bid = blockIdx.x, tid = threadIdx.x;
  const int wv = tid >> 6, l = tid & 63;
  const int lb = l & 15, kof = (l >> 4) * 8;
  const int drb = (l >> 4) * 4;

  if (bid >= 96) {
    if (bid < 608) {
      // -------- Xg0 = embed[ys] @ Wih0^T + bsum0 (coherent stores + counter)
      int g = bid - 96, mt = g >> 5, nt = g & 31;
      gemm_tile<1, false, true>(embedb, Wih0b, ys, bsum0, Xg0, 2048,
                                mt * 64, nt * 64, tid);
      asm volatile("s_waitcnt vmcnt(0)" ::: "memory");
      __syncthreads();
      if (tid == 0)
        __hip_atomic_fetch_add(xcnt + mt, 1, __ATOMIC_RELAXED, __HIP_MEMORY_SCOPE_AGENT);
    } else if (bid < 1008) {
      // -------- enc_p = hs @ W_enc^T + b_enc (read by next kernel: plain ok)
      int g = bid - 608, mt = g >> 3, nt = g & 7;
      gemm_tile<0, false, false>(hsb, Wencb, nullptr, b_enc, enc_p, 512,
                                 mt * 64, nt * 64, tid);
    } else {
      // -------- dec_p = Hdec @ W_dec^T (waits on L1 flags; coherent A loads)
      int g = bid - 1008, mt = g >> 3, nt = g & 7;
      const int need = mt * 4 + 4;
      if (tid < 64) {
        for (;;) {
          int a = __hip_atomic_load((int*)(flags1 + tid * 16), __ATOMIC_RELAXED, __HIP_MEMORY_SCOPE_AGENT);
          if (__all(a >= need)) break;
          __builtin_amdgcn_s_sleep(8);
        }
        __builtin_amdgcn_fence(__ATOMIC_ACQUIRE, "agent");
      }
      __syncthreads();
      gemm_tile<0, true, false>(Hdec, Wdecb, nullptr, nullptr, dec_p, 512,
                                mt * 64, nt * 64, tid);
    }
    return;
  }

  if (bid < L0WG) {
    // ---------------- layer 0: units [16*bid, +16)
    const int be = tid >> 4, je = tid & 15, jg = (bid << 4) + je;
    short8 breg[16];
#pragma unroll
    for (int g = 0; g < 4; ++g) {
      const u16* bp = Whh0 + (size_t)(g * 512 + bid * 16 + lb) * 512 + wv * 128 + kof;
#pragma unroll
      for (int ks = 0; ks < 4; ++ks)
        breg[g * 4 + ks] = *(const short8*)(bp + ks * 32);
    }
    float c0 = 0.f;
    for (int t = 0; t < 64; ++t) {
      waitflags(flags0, flags1, xcnt + (t >> 2), t, (t > 7) ? (t - 7) : 0, 32);
      // Xg0 loads (coherent; overlap with h loads below)
      const float* xg = Xg0 + (size_t)((t << 4) + be) * 2048 + jg;
      float x0 = __hip_atomic_load((float*)(xg),        __ATOMIC_RELAXED, __HIP_MEMORY_SCOPE_AGENT);
      float x1 = __hip_atomic_load((float*)(xg + 512),  __ATOMIC_RELAXED, __HIP_MEMORY_SCOPE_AGENT);
      float x2 = __hip_atomic_load((float*)(xg + 1024), __ATOMIC_RELAXED, __HIP_MEMORY_SCOPE_AGENT);
      float x3 = __hip_atomic_load((float*)(xg + 1536), __ATOMIC_RELAXED, __HIP_MEMORY_SCOPE_AGENT);
      const int rs = (t + 7) & 7;
      f32x4 g0 = {0.f,0.f,0.f,0.f}, g1 = g0, g2 = g0, g3 = g0;
#pragma unroll
      for (int ks = 0; ks < 4; ++ks) {
        int kk = wv * 128 + ks * 32 + kof;
        short8 av = ald16(haddr(h0b, rs, kk, lb));
        g0 = __builtin_amdgcn_mfma_f32_16x16x32_bf16(av, breg[0 * 4 + ks], g0, 0, 0, 0);
        g1 = __builtin_amdgcn_mfma_f32_16x16x32_bf16(av, breg[1 * 4 + ks], g1, 0, 0, 0);
        g2 = __builtin_amdgcn_mfma_f32_16x16x32_bf16(av, breg[2 * 4 + ks], g2, 0, 0, 0);
        g3 = __builtin_amdgcn_mfma_f32_16x16x32_bf16(av, breg[3 * 4 + ks], g3, 0, 0, 0);
      }
      f32x4 gs[4] = {g0, g1, g2, g3};
#pragma unroll
      for (int g = 0; g < 4; ++g)
#pragma unroll
        for (int i2 = 0; i2 < 4; ++i2)
          red[wv * 4 + g][(drb + i2) * 16 + lb] = gs[g][i2];
      __syncthreads();
      {
        float s0 = 0, s1 = 0, s2 = 0, s3 = 0;
#pragma unroll
        for (int v2 = 0; v2 < 4; ++v2) {
          s0 += red[v2 * 4 + 0][be * 16 + je]; s1 += red[v2 * 4 + 1][be * 16 + je];
          s2 += red[v2 * 4 + 2][be * 16 + je]; s3 += red[v2 * 4 + 3][be * 16 + je];
        }
        float gi = s0 + x0, gf = s1 + x1, gg = s2 + x2, go = s3 + x3;
        float I = sigm(gi), F = sigm(gf), G = tanh_c(gg), O = sigm(go);
        c0 = F * c0 + I * G;
        float h0 = O * tanh_c(c0);
        hstore(h0b, ((t & 7) * 32 + bid) * 256 + (tid & ~1), f2bf(h0), tid);
      }
      postflag(flags0 + bid * 16, t + 1);
    }
  } else {
    // ---------------- layer 1: units [8v, +8), v = bid-32
    const int v = bid - L0WG;
    const u16* base0 = (wv < 2) ? Wih1 : Whh1;
    const int kbase = (wv & 1) * 256;
    short8 breg[16];
#pragma unroll
    for (int tt = 0; tt < 2; ++tt) {
      int c = tt * 16 + lb, gate = c >> 3, du = c & 7;
      const u16* bp = base0 + (size_t)(gate * 512 + v * 8 + du) * 512 + kbase + kof;
#pragma unroll
      for (int ks = 0; ks < 8; ++ks)
        breg[tt * 8 + ks] = *(const short8*)(bp + ks * 32);
    }
    float bs0 = 0, bs1 = 0, bs2 = 0, bs3 = 0, c1 = 0.f;
    if (tid < 128) {
      int du = tid & 7, ju = v * 8 + du;
      bs0 = bsum1[ju]; bs1 = bsum1[512 + ju]; bs2 = bsum1[1024 + ju]; bs3 = bsum1[1536 + ju];
    }
    for (int t = 0; t < 64; ++t) {
      waitflags(flags0, flags1, nullptr, t + 1, t, 0);
      const u16* hsrc = (wv < 2) ? (h0b + (t & 7) * 8192) : (h1b + ((t + 7) & 7) * 8192);
      f32x4 g0 = {0.f,0.f,0.f,0.f}, g1 = g0;
#pragma unroll
      for (int ks = 0; ks < 8; ++ks) {
        int kk = kbase + ks * 32 + kof;
        short8 av = ald16(hsrc + (kk >> 4) * 256 + lb * 16 + (kk & 15));
        g0 = __builtin_amdgcn_mfma_f32_16x16x32_bf16(av, breg[0 * 8 + ks], g0, 0, 0, 0);
        g1 = __builtin_amdgcn_mfma_f32_16x16x32_bf16(av, breg[1 * 8 + ks], g1, 0, 0, 0);
      }
#pragma unroll
      for (int i2 = 0; i2 < 4; ++i2) {
        red[wv * 2 + 0][(drb + i2) * 16 + lb] = g0[i2];
        red[wv * 2 + 1][(drb + i2) * 16 + lb] = g1[i2];
      }
      __syncthreads();
      if (tid < 128) {
        int be = tid >> 3, du = tid & 7, ju = v * 8 + du;
        float sg[4] = {bs0, bs1, bs2, bs3};
#pragma unroll
        for (int g = 0; g < 4; ++g) {
          int c = g * 8 + du, tt = c >> 4, cc = c & 15;
          float acc = 0.f;
#pragma unroll
          for (int w2 = 0; w2 < 4; ++w2) acc += red[w2 * 2 + tt][be * 16 + cc];
          sg[g] += acc;
        }
        float I = sigm(sg[0]), F = sigm(sg[1]), G = tanh_c(sg[2]), O = sigm(sg[3]);
        c1 = F * c1 + I * G;
        float h1v = O * tanh_c(c1);
        u16 hb = f2bf(h1v);
        int idx = ((t & 7) * 32 + (ju >> 4)) * 256 + be * 16 + (ju & 15);
        hstore(h1b, idx & ~1, hb, tid);
        // Hdec BEFORE postflag (coherent, pair-packed) so dec_p sees it
        hstore(Hdec, ((t << 4) + be) * 512 + (ju & ~1), hb, tid);
      }
      postflag(flags1 + v * 16, t + 1);
    }
  }
}

// ---------------------------------------------------------------- joint
// r13 joint (proven 297us): 256 thr (2Mx2N), M=64, N=320, W/z dbuf 48KB,
// prefetch distance 2, NT epilogue.
__global__ __launch_bounds__(256) void joint_kernel(
    const float* __restrict__ enc_p,   // [16*200][512]
    const float* __restrict__ dec_p,   // [64*16][512]  row = u*16+b
    const u16* __restrict__ Wshuf,     // [32 kc][20 tile][64 lane][8] bf16
    const float* __restrict__ boutp,   // [640]
    float* __restrict__ out)
{
  __shared__ int4 wlds[2][1280];
  __shared__ int4 zlds[2][256];
  int bid = blockIdx.x;
  int b = bid / 400, rem = bid % 400;
  int tb = rem / 8, rem2 = rem % 8;
  int ub = rem2 >> 1, nh = rem2 & 1;
  int tid = threadIdx.x, wv = tid >> 6, l = tid & 63;
  int mv = wv >> 1, nv = wv & 1;
  int ln31 = l & 31, lh = l >> 5;
  const int tile0 = nv * 5;
  f32x16 acc[5];
#pragma unroll
  for (int j = 0; j < 5; ++j) {
    float bv = boutp[nh * 320 + (tile0 + j) * 32 + ln31];
#pragma unroll
    for (int g = 0; g < 16; ++g) acc[j][g] = bv;
  }
  int zr = tid & 63, zg = tid >> 6;
  const float* er = enc_p + (size_t)(b * 200 + tb * 4 + (zr >> 4)) * 512 + zg * 8;
  const float* dr = dec_p + (size_t)((ub * 16 + (zr & 15)) * 16 + b) * 512 + zg * 8;
  const int zslot = ((zg >> 1) * 2 + (zr >> 5)) * 64 + ((zg & 1) << 5) + (zr & 31);
  const int4* gW = (const int4*)Wshuf;
  const int nhof = nh * 640;
  const int L0 = tid, L1 = 256 + tid, L2 = 512 + tid + ((tid >= 128) ? 640 : 0),
            L3 = 1408 + tid, L4 = 1664 + tid;
  const int S2 = 512 + tid;

  int4 aw0, aw1, aw2, aw3, aw4; float4 ae0, ae1, ad0, ad1;
  int4 bw0, bw1, bw2, bw3, bw4; float4 be0, be1, bd0, bd1;

  {
    int4 w0 = gW[nhof + L0], w1 = gW[nhof + L1], w2 = gW[nhof + L2],
         w3 = gW[nhof + L3], w4 = gW[nhof + L4];
    float4 e0 = *(const float4*)(er),     e1 = *(const float4*)(er + 4);
    float4 d0 = *(const float4*)(dr),     d1 = *(const float4*)(dr + 4);
    const int cb1 = 2560 + nhof;
    aw0 = gW[cb1 + L0]; aw1 = gW[cb1 + L1]; aw2 = gW[cb1 + L2];
    aw3 = gW[cb1 + L3]; aw4 = gW[cb1 + L4];
    ae0 = *(const float4*)(er + 32); ae1 = *(const float4*)(er + 36);
    ad0 = *(const float4*)(dr + 32); ad1 = *(const float4*)(dr + 36);
    int4 pk;
    pk.x = (int)tj2(e0.x + d0.x, e0.y + d0.y);
    pk.y = (int)tj2(e0.z + d0.z, e0.w + d0.w);
    pk.z = (int)tj2(e1.x + d1.x, e1.y + d1.y);
    pk.w = (int)tj2(e1.z + d1.z, e1.w + d1.w);
    zlds[0][zslot] = pk;
    wlds[0][tid] = w0; wlds[0][256 + tid] = w1; wlds[0][S2] = w2;
    wlds[0][768 + tid] = w3; wlds[0][1024 + tid] = w4;
    __syncthreads();
  }

#define JBODY(C, CUR, NXT, W0, W1, W2, W3, W4, E0, E1, D0, D1,                  \
              PW0, PW1, PW2, PW3, PW4, PE0, PE1, PD0, PD1)                      \
  {                                                                             \
    if ((C) + 2 <= 15) {                                                        \
      const int cb = ((C) + 2) * 2560 + nhof;                                   \
      PW0 = gW[cb + L0]; PW1 = gW[cb + L1]; PW2 = gW[cb + L2];                  \
      PW3 = gW[cb + L3]; PW4 = gW[cb + L4];                                     \
      int k0 = ((C) + 2) * 32;                                                  \
      PE0 = *(const float4*)(er + k0); PE1 = *(const float4*)(er + k0 + 4);     \
      PD0 = *(const float4*)(dr + k0); PD1 = *(const float4*)(dr + k0 + 4);     \
    }                                                                           \
    _Pragma("unroll")                                                           \
    for (int ks = 0; ks < 2; ++ks) {                                            \
      short8 aA = *(const short8*)&zlds[CUR][(ks * 2 + mv) * 64 + l];           \
      _Pragma("unroll")                                                         \
      for (int j = 0; j < 5; ++j) {                                             \
        short8 bw = *(const short8*)&wlds[CUR][ks * 640 + (tile0 + j) * 64 + l];\
        acc[j] = __builtin_amdgcn_mfma_f32_32x32x16_bf16(aA, bw, acc[j], 0, 0, 0); \
      }                                                                         \
    }                                                                           \
    if ((C) + 1 <= 15) {                                                        \
      wlds[NXT][tid] = W0; wlds[NXT][256 + tid] = W1; wlds[NXT][S2] = W2;       \
      wlds[NXT][768 + tid] = W3; wlds[NXT][1024 + tid] = W4;                    \
      int4 pk;                                                                  \
      pk.x = (int)tj2(E0.x + D0.x, E0.y + D0.y);                                \
      pk.y = (int)tj2(E0.z + D0.z, E0.w + D0.w);                                \
      pk.z = (int)tj2(E1.x + D1.x, E1.y + D1.y);                                \
      pk.w = (int)tj2(E1.z + D1.z, E1.w + D1.w);                                \
      zlds[NXT][zslot] = pk;                                                    \
    }                                                                           \
    __syncthreads();                                                            \
  }

  for (int cc = 0; cc < 8; ++cc) {
    const int c0 = cc * 2;
    JBODY(c0,     0, 1, aw0, aw1, aw2, aw3, aw4, ae0, ae1, ad0, ad1,
                        bw0, bw1, bw2, bw3, bw4, be0, be1, bd0, bd1);
    JBODY(c0 + 1, 1, 0, bw0, bw1, bw2, bw3, bw4, be0, be1, bd0, bd1,
                        aw0, aw1, aw2, aw3, aw4, ae0, ae1, ad0, ad1);
  }
#undef JBODY

#pragma unroll
  for (int j = 0; j < 5; ++j) {
    int n = nh * 320 + (tile0 + j) * 32 + ln31;
    if (n < 600) {
      int rbase = mv * 32 + 4 * lh;
#pragma unroll
      for (int g = 0; g < 16; ++g) {
        int r = rbase + (g & 3) + ((g >> 2) << 3);
        int tt = tb * 4 + (r >> 4), uu = ub * 16 + (r & 15);
        __builtin_nontemporal_store(
            acc[j][g], &out[(size_t)((b * 200 + tt) * 64 + uu) * 600 + n]);
      }
    }
  }
}

// ---------------------------------------------------------------- host
extern "C" void kernel_launch(void* const* d_in, const int* in_sizes, int n_in,
                              void* d_out, int out_size, void* d_ws, size_t ws_size,
                              hipStream_t stream) {
  const float* hs_pad = (const float*)d_in[0];
  const int*   ys     = (const int*)d_in[1];
  const float* embed  = (const float*)d_in[2];
  const float* W_ih0  = (const float*)d_in[3];
  const float* W_hh0  = (const float*)d_in[4];
  const float* b_ih0  = (const float*)d_in[5];
  const float* b_hh0  = (const float*)d_in[6];
  const float* W_ih1  = (const float*)d_in[7];
  const float* W_hh1  = (const float*)d_in[8];
  const float* b_ih1  = (const float*)d_in[9];
  const float* b_hh1  = (const float*)d_in[10];
  const float* W_enc  = (const float*)d_in[11];
  const float* b_enc  = (const float*)d_in[12];
  const float* W_dec  = (const float*)d_in[13];
  const float* W_out  = (const float*)d_in[14];
  const float* b_out  = (const float*)d_in[15];
  float* out = (float*)d_out;

  uint8_t* ws = (uint8_t*)d_ws;
  size_t off = 0;
  auto alloc = [&](size_t bytes) -> void* {
    void* p = ws + off;
    off = (off + bytes + 255) & ~(size_t)255;
    return p;
  };
  int* flags0   = (int*)alloc(2048);                     // 32 slots x 64B
  int* flags1   = (int*)alloc(4096);                     // 64 slots x 64B
  int* xcnt     = (int*)alloc(256);                      // 16 m-tile counters
  u16* h0buf    = (u16*)alloc(8 * 32 * 256 * 2);         // 128 KB ring
  u16* h1buf    = (u16*)alloc(8 * 32 * 256 * 2);         // 128 KB ring
  u16* Hdec     = (u16*)alloc(64 * 16 * 512 * 2);        // 1 MB
  float* Xg0    = (float*)alloc(1024 * 2048 * 4);        // 8 MB
  float* enc_p  = (float*)alloc(3200 * 512 * 4);         // 6.5 MB
  float* dec_p  = (float*)alloc(1024 * 512 * 4);         // 2 MB
  u16* Wih0b    = (u16*)alloc(2048 * 512 * 2);
  u16* Whh0b    = (u16*)alloc(2048 * 512 * 2);
  u16* Wih1b    = (u16*)alloc(2048 * 512 * 2);
  u16* Whh1b    = (u16*)alloc(2048 * 512 * 2);
  u16* Wencb    = (u16*)alloc(512 * 512 * 2);
  u16* Wdecb    = (u16*)alloc(512 * 512 * 2);
  u16* embedb   = (u16*)alloc(600 * 512 * 2);
  u16* hsb      = (u16*)alloc(3200 * 512 * 2);
  u16* Wshufb   = (u16*)alloc(32 * 20 * 64 * 8 * 2);
  float* bsum0  = (float*)alloc(2048 * 4);
  float* bsum1  = (float*)alloc(2048 * 4);
  float* boutp  = (float*)alloc(640 * 4);

  // zero flags0+flags1+xcnt+h rings (contiguous: 2048+4096+256+128K+128K)
  (void)hipMemsetAsync(d_ws, 0, 2048 + 4096 + 256 + 131072 + 131072, stream);

  prep_kernel<<<2048, 256, 0, stream>>>(
      W_ih0, W_hh0, W_ih1, W_hh1, W_enc, W_dec, W_out, embed, hs_pad,
      b_ih0, b_hh0, b_ih1, b_hh1, b_out,
      Wih0b, Whh0b, Wih1b, Whh1b, Wencb, Wdecb, embedb, hsb, Wshufb,
      bsum0, bsum1, boutp);

  // fused: Xg0 GEMM + enc_p GEMM + 2-layer LSTM + dec_p GEMM (one launch)
  lstm_fused<<<FUSED_WG, 256, 0, stream>>>(
      embedb, Wih0b, ys, bsum0, Xg0,
      hsb, Wencb, b_enc, enc_p,
      Wdecb, dec_p,
      Whh0b, Wih1b, Whh1b, bsum1,
      h0buf, h1buf, Hdec, flags0, flags1, xcnt);

  // big fused joint (r13: prefetch-2 + NT epilogue)
  joint_kernel<<<6400, 256, 0, stream>>>(enc_p, dec_p, Wshufb, boutp, out);
}

// Round 15
// 613.970 us; speedup vs baseline: 1.0180x; 1.0180x over previous
//
#include <hip/hip_runtime.h>
#include <hip/hip_bf16.h>
#include <stdint.h>

#define DEVI __device__ __forceinline__

typedef unsigned short u16;
typedef __attribute__((ext_vector_type(8))) short short8;
typedef __attribute__((ext_vector_type(4))) float f32x4;
typedef __attribute__((ext_vector_type(16))) float f32x16;

DEVI u16 f2bf(float f) {
  union { float f; uint32_t u; } v; v.f = f;
  return (u16)((v.u + 0x7fffu + ((v.u >> 16) & 1u)) >> 16);
}
DEVI float tanh_c(float x) {
  float e = __expf(x + x);
  float r = __builtin_amdgcn_rcpf(e + 1.0f);
  return __builtin_fmaf(-2.0f, r, 1.0f);
}
DEVI float sigm(float x) { return __builtin_amdgcn_rcpf(1.0f + __expf(-x)); }
DEVI uint32_t tj2(float a, float b) {
  float ea = __expf(a + a), eb = __expf(b + b);
  float ta = __builtin_fmaf(-2.0f, __builtin_amdgcn_rcpf(ea + 1.0f), 1.0f);
  float tb = __builtin_fmaf(-2.0f, __builtin_amdgcn_rcpf(eb + 1.0f), 1.0f);
  union { __hip_bfloat162 h; uint32_t u; } cv;
  cv.h = __float22bfloat162_rn(make_float2(ta, tb));
  return cv.u;
}
DEVI short8 ald16(const u16* p) {
  union { unsigned long long q[2]; short8 v; } u;
  u.q[0] = __hip_atomic_load((unsigned long long*)p,       __ATOMIC_RELAXED, __HIP_MEMORY_SCOPE_AGENT);
  u.q[1] = __hip_atomic_load((unsigned long long*)(p + 4), __ATOMIC_RELAXED, __HIP_MEMORY_SCOPE_AGENT);
  return u.v;
}
// coherent float4 load (2 x u64 atomics) -- same-kernel cross-XCD reads
DEVI float4 aldf4(const float* p) {
  union { unsigned long long q[2]; float4 v; } u;
  u.q[0] = __hip_atomic_load((unsigned long long*)p,       __ATOMIC_RELAXED, __HIP_MEMORY_SCOPE_AGENT);
  u.q[1] = __hip_atomic_load((unsigned long long*)(p + 2), __ATOMIC_RELAXED, __HIP_MEMORY_SCOPE_AGENT);
  return u.v;
}

// ---------------------------------------------------------------- prep
__global__ void prep_kernel(
    const float* __restrict__ W_ih0, const float* __restrict__ W_hh0,
    const float* __restrict__ W_ih1, const float* __restrict__ W_hh1,
    const float* __restrict__ W_enc, const float* __restrict__ W_dec,
    const float* __restrict__ W_out, const float* __restrict__ embed,
    const float* __restrict__ hs_pad,
    const float* __restrict__ b_ih0, const float* __restrict__ b_hh0,
    const float* __restrict__ b_ih1, const float* __restrict__ b_hh1,
    const float* __restrict__ b_out,
    u16* __restrict__ Wih0b, u16* __restrict__ Whh0b,
    u16* __restrict__ Wih1b, u16* __restrict__ Whh1b,
    u16* __restrict__ Wencb, u16* __restrict__ Wdecb,
    u16* __restrict__ embedb, u16* __restrict__ hsb,
    u16* __restrict__ Wshufb,
    float* __restrict__ bsum0, float* __restrict__ bsum1, float* __restrict__ boutp)
{
  const int c1 = 1048576, c2 = 2097152, c3 = 3145728, c4 = 4194304;
  const int c5 = 4456448, c6 = 4718592, c7 = 5025792, c8 = 6664192;
  const int c9 = 6991872, c10 = 6993920, c11 = 6995968, c12 = 6996608;
  for (int i = blockIdx.x * blockDim.x + threadIdx.x; i < c12; i += gridDim.x * blockDim.x) {
    if (i < c1)       Wih0b[i]      = f2bf(W_ih0[i]);
    else if (i < c2)  Whh0b[i - c1] = f2bf(W_hh0[i - c1]);
    else if (i < c3)  Wih1b[i - c2] = f2bf(W_ih1[i - c2]);
    else if (i < c4)  Whh1b[i - c3] = f2bf(W_hh1[i - c3]);
    else if (i < c5)  Wencb[i - c4] = f2bf(W_enc[i - c4]);
    else if (i < c6)  Wdecb[i - c5] = f2bf(W_dec[i - c5]);
    else if (i < c7)  embedb[i - c6] = f2bf(embed[i - c6]);
    else if (i < c8)  hsb[i - c7]   = f2bf(hs_pad[i - c7]);
    else if (i < c9) {
      int e = i - c8;
      int kc = e / 10240, r = e % 10240;
      int tile = r >> 9, r2 = r & 511;
      int lane = r2 >> 3, ii = r2 & 7;
      int n = tile * 32 + (lane & 31);
      int k = kc * 16 + ((lane >> 5) << 3) + ii;
      Wshufb[e] = (n < 600) ? f2bf(W_out[n * 512 + k]) : (u16)0;
    }
    else if (i < c10) { int n = i - c9;  bsum0[n] = b_ih0[n] + b_hh0[n]; }
    else if (i < c11) { int n = i - c10; bsum1[n] = b_ih1[n] + b_hh1[n]; }
    else              { int n = i - c11; boutp[n] = (n < 600) ? b_out[n] : 0.0f; }
  }
}

// ---------------------------------------------- 64x64 MFMA GEMM tile (device)
template<int MODE, bool AAT, bool SAT>
DEVI void gemm_tile(const u16* __restrict__ A, const u16* __restrict__ B,
                    const int* __restrict__ ys, const float* __restrict__ bias,
                    float* __restrict__ out, int N, int m0, int n0, int tid)
{
  int wv = tid >> 6, l = tid & 63;
  int row = m0 + wv * 16 + (l & 15);
  const u16* arow;
  if (MODE == 1) { int uu = row >> 4, bb = row & 15; arow = A + (size_t)ys[bb * 64 + uu] * 512; }
  else           arow = A + (size_t)row * 512;
  int kof = (l >> 4) * 8;
  arow += kof;
  const u16* br = B + (size_t)(n0 + (l & 15)) * 512 + kof;
  f32x4 a0 = {0.f,0.f,0.f,0.f}, a1 = a0, a2 = a0, a3 = a0;
  for (int kk = 0; kk < 512; kk += 32) {
    short8 av = AAT ? ald16(arow + kk) : *(const short8*)(arow + kk);
    short8 b0 = *(const short8*)(br + kk);
    short8 b1 = *(const short8*)(br + 8192 + kk);
    short8 b2 = *(const short8*)(br + 16384 + kk);
    short8 b3 = *(const short8*)(br + 24576 + kk);
    a0 = __builtin_amdgcn_mfma_f32_16x16x32_bf16(av, b0, a0, 0, 0, 0);
    a1 = __builtin_amdgcn_mfma_f32_16x16x32_bf16(av, b1, a1, 0, 0, 0);
    a2 = __builtin_amdgcn_mfma_f32_16x16x32_bf16(av, b2, a2, 0, 0, 0);
    a3 = __builtin_amdgcn_mfma_f32_16x16x32_bf16(av, b3, a3, 0, 0, 0);
  }
  int col = l & 15, rb = m0 + wv * 16 + (l >> 4) * 4;
  f32x4 accs[4] = {a0, a1, a2, a3};
#pragma unroll
  for (int g = 0; g < 4; ++g) {
    int n = n0 + g * 16 + col;
    float bs = bias ? bias[n] : 0.0f;
#pragma unroll
    for (int i2 = 0; i2 < 4; ++i2) {
      float v = accs[g][i2] + bs;
      if (SAT)
        __hip_atomic_store(&out[(size_t)(rb + i2) * N + n], v,
                           __ATOMIC_RELAXED, __HIP_MEMORY_SCOPE_AGENT);
      else
        out[(size_t)(rb + i2) * N + n] = v;
    }
  }
}

// --------------------------------------------- pre-GEMMs: Xg0 + enc_p (plain)
__global__ __launch_bounds__(256) void gemm_pre(
    const u16* __restrict__ embedb, const u16* __restrict__ Wih0b,
    const int* __restrict__ ys, const float* __restrict__ bsum0,
    float* __restrict__ Xg0,
    const u16* __restrict__ hsb, const u16* __restrict__ Wencb,
    const float* __restrict__ b_enc, float* __restrict__ enc_p)
{
  int bid = blockIdx.x, tid = threadIdx.x;
  if (bid < 512) {
    int mt = bid >> 5, nt = bid & 31;
    gemm_tile<1, false, false>(embedb, Wih0b, ys, bsum0, Xg0, 2048,
                               mt * 64, nt * 64, tid);
  } else {
    int g = bid - 512, mt = g >> 3, nt = g & 7;
    gemm_tile<0, false, false>(hsb, Wencb, nullptr, b_enc, enc_p, 512,
                               mt * 64, nt * 64, tid);
  }
}

// ---------------------------------------------------------------- mega kernel
// bid 0..95:    LSTM (r13-exact protocol; Hdec coherent store pre-flag)
// bid 96..223:  dec_p GEMM (gated on flags1; coherent loads+stores; dcnt++)
// bid 224..6623: joint tiles, ub-outermost, gated on dcnt[ub]==32
#define L0WG 32
#define MEGA_WG 6624

DEVI void waitflags(const int* f0, const int* f1, int n0, int n1) {
  if (threadIdx.x < 64) {
    int l = threadIdx.x;
    for (;;) {
      int a = __hip_atomic_load((int*)(f0 + (l & 31) * 16), __ATOMIC_RELAXED, __HIP_MEMORY_SCOPE_AGENT);
      int b = __hip_atomic_load((int*)(f1 + l * 16),        __ATOMIC_RELAXED, __HIP_MEMORY_SCOPE_AGENT);
      if (__all(a >= n0 && b >= n1)) break;
      __builtin_amdgcn_s_sleep(1);
    }
    __builtin_amdgcn_fence(__ATOMIC_ACQUIRE, "agent");
  }
  __syncthreads();
}
DEVI void postflag(int* slot, int val) {
  __syncthreads();
  if (threadIdx.x == 0) {
    asm volatile("s_waitcnt vmcnt(0)" ::: "memory");
    __hip_atomic_store(slot, val, __ATOMIC_RELAXED, __HIP_MEMORY_SCOPE_AGENT);
  }
}
DEVI const u16* haddr(const u16* base, int slot, int k, int b) {
  return base + slot * 8192 + (k >> 4) * 256 + b * 16 + (k & 15);
}
DEVI void hstore(u16* base, int idx, u16 mine, int tid) {
  int other = __shfl_xor((int)mine, 1);
  if (!(tid & 1)) {
    uint32_t pkv = (uint32_t)mine | (((uint32_t)other & 0xffffu) << 16);
    __hip_atomic_store((uint32_t*)(base + idx), pkv, __ATOMIC_RELAXED, __HIP_MEMORY_SCOPE_AGENT);
  }
}

__global__ __launch_bounds__(256) void mega_kernel(
    const float* __restrict__ Xg0,
    const u16* __restrict__ Whh0, const u16* __restrict__ Wih1, const u16* __restrict__ Whh1,
    const float* __restrict__ bsum1,
    u16* __restrict__ h0b, u16* __restrict__ h1b,
    u16* __restrict__ Hdec,
    const u16* __restrict__ Wdecb, float* __restrict__ dec_p,
    const float* __restrict__ enc_p, const u16* __restrict__ Wshuf,
    const float* __restrict__ boutp, float* __restrict__ out,
    int* __restrict__ flags0, int* __restrict__ flags1, int* __restrict__ dcnt)
{
  __shared__ int4 smem[3072];   // 48KB union: joint wlds+zlds | LSTM red[16][256]
  const int bid = blockIdx.x, tid = threadIdx.x;
  const int wv = tid >> 6, l = tid & 63;

  if (bid >= 224) {
    // ================= joint tile, gated on dcnt[ub] =================
    int jbid = bid - 224;
    int ub = jbid / 1600, rem = jbid % 1600;
    int b = rem / 100, r2 = rem % 100;
    int tb = r2 >> 1, nh = r2 & 1;
    if (tid == 0) {
      for (;;) {
        int c = __hip_atomic_load(dcnt + ub * 16, __ATOMIC_RELAXED, __HIP_MEMORY_SCOPE_AGENT);
        if (c >= 32) break;
        __builtin_amdgcn_s_sleep(32);
      }
      __builtin_amdgcn_fence(__ATOMIC_ACQUIRE, "agent");
    }
    __syncthreads();

    int4 (*wlds)[1280] = (int4(*)[1280])smem;
    int4 (*zlds)[256]  = (int4(*)[256])(smem + 2560);
    int mv = wv >> 1, nv = wv & 1;
    int ln31 = l & 31, lh = l >> 5;
    const int tile0 = nv * 5;
    f32x16 acc[5];
#pragma unroll
    for (int j = 0; j < 5; ++j) {
      float bv = boutp[nh * 320 + (tile0 + j) * 32 + ln31];
#pragma unroll
      for (int g = 0; g < 16; ++g) acc[j][g] = bv;
    }
    int zr = tid & 63, zg = tid >> 6;
    const float* er = enc_p + (size_t)(b * 200 + tb * 4 + (zr >> 4)) * 512 + zg * 8;
    const float* dr = dec_p + (size_t)((ub * 16 + (zr & 15)) * 16 + b) * 512 + zg * 8;
    const int zslot = ((zg >> 1) * 2 + (zr >> 5)) * 64 + ((zg & 1) << 5) + (zr & 31);
    const int4* gW = (const int4*)Wshuf;
    const int nhof = nh * 640;
    const int L0 = tid, L1 = 256 + tid, L2 = 512 + tid + ((tid >= 128) ? 640 : 0),
              L3 = 1408 + tid, L4 = 1664 + tid;
    const int S2 = 512 + tid;

    int4 aw0, aw1, aw2, aw3, aw4; float4 ae0, ae1, ad0, ad1;
    int4 bw0, bw1, bw2, bw3, bw4; float4 be0, be1, bd0, bd1;

    {
      int4 w0 = gW[nhof + L0], w1 = gW[nhof + L1], w2 = gW[nhof + L2],
           w3 = gW[nhof + L3], w4 = gW[nhof + L4];
      float4 e0 = *(const float4*)(er),  e1 = *(const float4*)(er + 4);
      float4 d0 = aldf4(dr),             d1 = aldf4(dr + 4);
      const int cb1 = 2560 + nhof;
      aw0 = gW[cb1 + L0]; aw1 = gW[cb1 + L1]; aw2 = gW[cb1 + L2];
      aw3 = gW[cb1 + L3]; aw4 = gW[cb1 + L4];
      ae0 = *(const float4*)(er + 32); ae1 = *(const float4*)(er + 36);
      ad0 = aldf4(dr + 32);            ad1 = aldf4(dr + 36);
      int4 pk;
      pk.x = (int)tj2(e0.x + d0.x, e0.y + d0.y);
      pk.y = (int)tj2(e0.z + d0.z, e0.w + d0.w);
      pk.z = (int)tj2(e1.x + d1.x, e1.y + d1.y);
      pk.w = (int)tj2(e1.z + d1.z, e1.w + d1.w);
      zlds[0][zslot] = pk;
      wlds[0][tid] = w0; wlds[0][256 + tid] = w1; wlds[0][S2] = w2;
      wlds[0][768 + tid] = w3; wlds[0][1024 + tid] = w4;
      __syncthreads();
    }

#define JBODY(C, CUR, NXT, W0, W1, W2, W3, W4, E0, E1, D0, D1,                  \
              PW0, PW1, PW2, PW3, PW4, PE0, PE1, PD0, PD1)                      \
  {                                                                             \
    if ((C) + 2 <= 15) {                                                        \
      const int cb = ((C) + 2) * 2560 + nhof;                                   \
      PW0 = gW[cb + L0]; PW1 = gW[cb + L1]; PW2 = gW[cb + L2];                  \
      PW3 = gW[cb + L3]; PW4 = gW[cb + L4];                                     \
      int k0 = ((C) + 2) * 32;                                                  \
      PE0 = *(const float4*)(er + k0); PE1 = *(const float4*)(er + k0 + 4);     \
      PD0 = aldf4(dr + k0);            PD1 = aldf4(dr + k0 + 4);                \
    }                                                                           \
    _Pragma("unroll")                                                           \
    for (int ks = 0; ks < 2; ++ks) {                                            \
      short8 aA = *(const short8*)&zlds[CUR][(ks * 2 + mv) * 64 + l];           \
      _Pragma("unroll")                                                         \
      for (int j = 0; j < 5; ++j) {                                             \
        short8 bw = *(const short8*)&wlds[CUR][ks * 640 + (tile0 + j) * 64 + l];\
        acc[j] = __builtin_amdgcn_mfma_f32_32x32x16_bf16(aA, bw, acc[j], 0, 0, 0); \
      }                                                                         \
    }                                                                           \
    if ((C) + 1 <= 15) {                                                        \
      wlds[NXT][tid] = W0; wlds[NXT][256 + tid] = W1; wlds[NXT][S2] = W2;       \
      wlds[NXT][768 + tid] = W3; wlds[NXT][1024 + tid] = W4;                    \
      int4 pk;                                                                  \
      pk.x = (int)tj2(E0.x + D0.x, E0.y + D0.y);                                \
      pk.y = (int)tj2(E0.z + D0.z, E0.w + D0.w);                                \
      pk.z = (int)tj2(E1.x + D1.x, E1.y + D1.y);                                \
      pk.w = (int)tj2(E1.z + D1.z, E1.w + D1.w);                                \
      zlds[NXT][zslot] = pk;                                                    \
    }                                                                           \
    __syncthreads();                                                            \
  }

    for (int cc = 0; cc < 8; ++cc) {
      const int c0 = cc * 2;
      JBODY(c0,     0, 1, aw0, aw1, aw2, aw3, aw4, ae0, ae1, ad0, ad1,
                          bw0, bw1, bw2, bw3, bw4, be0, be1, bd0, bd1);
      JBODY(c0 + 1, 1, 0, bw0, bw1, bw2, bw3, bw4, be0, be1, bd0, bd1,
                          aw0, aw1, aw2, aw3, aw4, ae0, ae1, ad0, ad1);
    }
#undef JBODY

#pragma unroll
    for (int j = 0; j < 5; ++j) {
      int n = nh * 320 + (tile0 + j) * 32 + ln31;
      if (n < 600) {
        int rbase = mv * 32 + 4 * lh;
#pragma unroll
        for (int g = 0; g < 16; ++g) {
          int r = rbase + (g & 3) + ((g >> 2) << 3);
          int tt = tb * 4 + (r >> 4), uu = ub * 16 + (r & 15);
          __builtin_nontemporal_store(
              acc[j][g], &out[(size_t)((b * 200 + tt) * 64 + uu) * 600 + n]);
        }
      }
    }
    return;
  }

  if (bid >= 96) {
    // ================= dec_p = Hdec @ W_dec^T (gated, coherent) =========
    int g = bid - 96, mt = g >> 3, nt = g & 7;
    const int need = mt * 4 + 4;
    if (tid < 64) {
      for (;;) {
        int a = __hip_atomic_load((int*)(flags1 + tid * 16), __ATOMIC_RELAXED, __HIP_MEMORY_SCOPE_AGENT);
        if (__all(a >= need)) break;
        __builtin_amdgcn_s_sleep(16);
      }
      __builtin_amdgcn_fence(__ATOMIC_ACQUIRE, "agent");
    }
    __syncthreads();
    gemm_tile<0, true, true>(Hdec, Wdecb, nullptr, nullptr, dec_p, 512,
                             mt * 64, nt * 64, tid);
    asm volatile("s_waitcnt vmcnt(0)" ::: "memory");
    __syncthreads();
    if (tid == 0)
      __hip_atomic_fetch_add(dcnt + (mt >> 2) * 16, 1, __ATOMIC_RELAXED, __HIP_MEMORY_SCOPE_AGENT);
    return;
  }

  // ===================== LSTM (r13-exact) =====================
  float (*red)[256] = (float(*)[256])smem;
  const int lb = l & 15, kof = (l >> 4) * 8;
  const int drb = (l >> 4) * 4;

  if (bid < L0WG) {
    const int be = tid >> 4, je = tid & 15, jg = (bid << 4) + je;
    short8 breg[16];
#pragma unroll
    for (int g = 0; g < 4; ++g) {
      const u16* bp = Whh0 + (size_t)(g * 512 + bid * 16 + lb) * 512 + wv * 128 + kof;
#pragma unroll
      for (int ks = 0; ks < 4; ++ks)
        breg[g * 4 + ks] = *(const short8*)(bp + ks * 32);
    }
    float c0 = 0.f;
    for (int t = 0; t < 64; ++t) {
      const float* xg = Xg0 + (size_t)((t << 4) + be) * 2048 + jg;
      float x0 = xg[0], x1 = xg[512], x2 = xg[1024], x3 = xg[1536];
      waitflags(flags0, flags1, t, (t > 7) ? (t - 7) : 0);
      const int rs = (t + 7) & 7;
      f32x4 g0 = {0.f,0.f,0.f,0.f}, g1 = g0, g2 = g0, g3 = g0;
#pragma unroll
      for (int ks = 0; ks < 4; ++ks) {
        int kk = wv * 128 + ks * 32 + kof;
        short8 av = ald16(haddr(h0b, rs, kk, lb));
        g0 = __builtin_amdgcn_mfma_f32_16x16x32_bf16(av, breg[0 * 4 + ks], g0, 0, 0, 0);
        g1 = __builtin_amdgcn_mfma_f32_16x16x32_bf16(av, breg[1 * 4 + ks], g1, 0, 0, 0);
        g2 = __builtin_amdgcn_mfma_f32_16x16x32_bf16(av, breg[2 * 4 + ks], g2, 0, 0, 0);
        g3 = __builtin_amdgcn_mfma_f32_16x16x32_bf16(av, breg[3 * 4 + ks], g3, 0, 0, 0);
      }
      f32x4 gs[4] = {g0, g1, g2, g3};
#pragma unroll
      for (int g = 0; g < 4; ++g)
#pragma unroll
        for (int i2 = 0; i2 < 4; ++i2)
          red[wv * 4 + g][(drb + i2) * 16 + lb] = gs[g][i2];
      __syncthreads();
      {
        float s0 = 0, s1 = 0, s2 = 0, s3 = 0;
#pragma unroll
        for (int v2 = 0; v2 < 4; ++v2) {
          s0 += red[v2 * 4 + 0][be * 16 + je]; s1 += red[v2 * 4 + 1][be * 16 + je];
          s2 += red[v2 * 4 + 2][be * 16 + je]; s3 += red[v2 * 4 + 3][be * 16 + je];
        }
        float gi = s0 + x0, gf = s1 + x1, gg = s2 + x2, go = s3 + x3;
        float I = sigm(gi), F = sigm(gf), G = tanh_c(gg), O = sigm(go);
        c0 = F * c0 + I * G;
        float h0 = O * tanh_c(c0);
        hstore(h0b, ((t & 7) * 32 + bid) * 256 + (tid & ~1), f2bf(h0), tid);
      }
      postflag(flags0 + bid * 16, t + 1);
    }
  } else {
    const int v = bid - L0WG;
    const u16* base0 = (wv < 2) ? Wih1 : Whh1;
    const int kbase = (wv & 1) * 256;
    short8 breg[16];
#pragma unroll
    for (int tt = 0; tt < 2; ++tt) {
      int c = tt * 16 + lb, gate = c >> 3, du = c & 7;
      const u16* bp = base0 + (size_t)(gate * 512 + v * 8 + du) * 512 + kbase + kof;
#pragma unroll
      for (int ks = 0; ks < 8; ++ks)
        breg[tt * 8 + ks] = *(const short8*)(bp + ks * 32);
    }
    float bs0 = 0, bs1 = 0, bs2 = 0, bs3 = 0, c1 = 0.f;
    if (tid < 128) {
      int du = tid & 7, ju = v * 8 + du;
      bs0 = bsum1[ju]; bs1 = bsum1[512 + ju]; bs2 = bsum1[1024 + ju]; bs3 = bsum1[1536 + ju];
    }
    for (int t = 0; t < 64; ++t) {
      waitflags(flags0, flags1, t + 1, t);
      const u16* hsrc = (wv < 2) ? (h0b + (t & 7) * 8192) : (h1b + ((t + 7) & 7) * 8192);
      f32x4 g0 = {0.f,0.f,0.f,0.f}, g1 = g0;
#pragma unroll
      for (int ks = 0; ks < 8; ++ks) {
        int kk = kbase + ks * 32 + kof;
        short8 av = ald16(hsrc + (kk >> 4) * 256 + lb * 16 + (kk & 15));
        g0 = __builtin_amdgcn_mfma_f32_16x16x32_bf16(av, breg[0 * 8 + ks], g0, 0, 0, 0);
        g1 = __builtin_amdgcn_mfma_f32_16x16x32_bf16(av, breg[1 * 8 + ks], g1, 0, 0, 0);
      }
#pragma unroll
      for (int i2 = 0; i2 < 4; ++i2) {
        red[wv * 2 + 0][(drb + i2) * 16 + lb] = g0[i2];
        red[wv * 2 + 1][(drb + i2) * 16 + lb] = g1[i2];
      }
      __syncthreads();
      if (tid < 128) {
        int be = tid >> 3, du = tid & 7, ju = v * 8 + du;
        float sg[4] = {bs0, bs1, bs2, bs3};
#pragma unroll
        for (int g = 0; g < 4; ++g) {
          int c = g * 8 + du, tt = c >> 4, cc = c & 15;
          float acc = 0.f;
#pragma unroll
          for (int w2 = 0; w2 < 4; ++w2) acc += red[w2 * 2 + tt][be * 16 + cc];
          sg[g] += acc;
        }
        float I = sigm(sg[0]), F = sigm(sg[1]), G = tanh_c(sg[2]), O = sigm(sg[3]);
        c1 = F * c1 + I * G;
        float h1v = O * tanh_c(c1);
        u16 hb = f2bf(h1v);
        int idx = ((t & 7) * 32 + (ju >> 4)) * 256 + be * 16 + (ju & 15);
        hstore(h1b, idx & ~1, hb, tid);
        // Hdec coherent, BEFORE postflag (vmcnt drain covers it)
        hstore(Hdec, ((t << 4) + be) * 512 + (ju & ~1), hb, tid);
      }
      postflag(flags1 + v * 16, t + 1);
    }
  }
}

// ---------------------------------------------------------------- host
extern "C" void kernel_launch(void* const* d_in, const int* in_sizes, int n_in,
                              void* d_out, int out_size, void* d_ws, size_t ws_size,
                              hipStream_t stream) {
  const float* hs_pad = (const float*)d_in[0];
  const int*   ys     = (const int*)d_in[1];
  const float* embed  = (const float*)d_in[2];
  const float* W_ih0  = (const float*)d_in[3];
  const float* W_hh0  = (const float*)d_in[4];
  const float* b_ih0  = (const float*)d_in[5];
  const float* b_hh0  = (const float*)d_in[6];
  const float* W_ih1  = (const float*)d_in[7];
  const float* W_hh1  = (const float*)d_in[8];
  const float* b_ih1  = (const float*)d_in[9];
  const float* b_hh1  = (const float*)d_in[10];
  const float* W_enc  = (const float*)d_in[11];
  const float* b_enc  = (const float*)d_in[12];
  const float* W_dec  = (const float*)d_in[13];
  const float* W_out  = (const float*)d_in[14];
  const float* b_out  = (const float*)d_in[15];
  float* out = (float*)d_out;

  uint8_t* ws = (uint8_t*)d_ws;
  size_t off = 0;
  auto alloc = [&](size_t bytes) -> void* {
    void* p = ws + off;
    off = (off + bytes + 255) & ~(size_t)255;
    return p;
  };
  int* flags0   = (int*)alloc(2048);                     // 32 slots x 64B
  int* flags1   = (int*)alloc(4096);                     // 64 slots x 64B
  int* dcnt     = (int*)alloc(256);                      // 4 ublock counters x 64B
  u16* h0buf    = (u16*)alloc(8 * 32 * 256 * 2);         // 128 KB ring
  u16* h1buf    = (u16*)alloc(8 * 32 * 256 * 2);         // 128 KB ring
  u16* Hdec     = (u16*)alloc(64 * 16 * 512 * 2);        // 1 MB
  float* Xg0    = (float*)alloc(1024 * 2048 * 4);        // 8 MB
  float* enc_p  = (float*)alloc(3200 * 512 * 4);         // 6.5 MB
  float* dec_p  = (float*)alloc(1024 * 512 * 4);         // 2 MB
  u16* Wih0b    = (u16*)alloc(2048 * 512 * 2);
  u16* Whh0b    = (u16*)alloc(2048 * 512 * 2);
  u16* Wih1b    = (u16*)alloc(2048 * 512 * 2);
  u16* Whh1b    = (u16*)alloc(2048 * 512 * 2);
  u16* Wencb    = (u16*)alloc(512 * 512 * 2);
  u16* Wdecb    = (u16*)alloc(512 * 512 * 2);
  u16* embedb   = (u16*)alloc(600 * 512 * 2);
  u16* hsb      = (u16*)alloc(3200 * 512 * 2);
  u16* Wshufb   = (u16*)alloc(32 * 20 * 64 * 8 * 2);
  float* bsum0  = (float*)alloc(2048 * 4);
  float* bsum1  = (float*)alloc(2048 * 4);
  float* boutp  = (float*)alloc(640 * 4);

  // zero flags0+flags1+dcnt+h rings (contiguous)
  (void)hipMemsetAsync(d_ws, 0, 2048 + 4096 + 256 + 131072 + 131072, stream);

  prep_kernel<<<2048, 256, 0, stream>>>(
      W_ih0, W_hh0, W_ih1, W_hh1, W_enc, W_dec, W_out, embed, hs_pad,
      b_ih0, b_hh0, b_ih1, b_hh1, b_out,
      Wih0b, Whh0b, Wih1b, Whh1b, Wencb, Wdecb, embedb, hsb, Wshufb,
      bsum0, bsum1, boutp);

  // Xg0 + enc_p in one launch (both plain; LSTM inputs fully materialized)
  gemm_pre<<<912, 256, 0, stream>>>(embedb, Wih0b, ys, bsum0, Xg0,
                                    hsb, Wencb, b_enc, enc_p);

  // mega: LSTM + gated dec_p + gated joint (consumer overlap)
  mega_kernel<<<MEGA_WG, 256, 0, stream>>>(
      Xg0, Whh0b, Wih1b, Whh1b, bsum1,
      h0buf, h1buf, Hdec, Wdecb, dec_p,
      enc_p, Wshufb, boutp, out,
      flags0, flags1, dcnt);
}

// Round 16
// 541.407 us; speedup vs baseline: 1.1545x; 1.1340x over previous
//
#include <hip/hip_runtime.h>
#include <hip/hip_bf16.h>
#include <stdint.h>

#define DEVI __device__ __forceinline__

typedef unsigned short u16;
typedef __attribute__((ext_vector_type(8))) short short8;
typedef __attribute__((ext_vector_type(4))) float f32x4;
typedef __attribute__((ext_vector_type(16))) float f32x16;

DEVI u16 f2bf(float f) {
  union { float f; uint32_t u; } v; v.f = f;
  return (u16)((v.u + 0x7fffu + ((v.u >> 16) & 1u)) >> 16);
}
DEVI float tanh_c(float x) {
  float e = __expf(x + x);
  float r = __builtin_amdgcn_rcpf(e + 1.0f);
  return __builtin_fmaf(-2.0f, r, 1.0f);
}
DEVI float sigm(float x) { return __builtin_amdgcn_rcpf(1.0f + __expf(-x)); }
DEVI uint32_t tj2(float a, float b) {
  float ea = __expf(a + a), eb = __expf(b + b);
  float ta = __builtin_fmaf(-2.0f, __builtin_amdgcn_rcpf(ea + 1.0f), 1.0f);
  float tb = __builtin_fmaf(-2.0f, __builtin_amdgcn_rcpf(eb + 1.0f), 1.0f);
  union { __hip_bfloat162 h; uint32_t u; } cv;
  cv.h = __float22bfloat162_rn(make_float2(ta, tb));
  return cv.u;
}

// ---------------------------------------------------------------- prep
__global__ void prep_kernel(
    const float* __restrict__ W_ih0, const float* __restrict__ W_hh0,
    const float* __restrict__ W_ih1, const float* __restrict__ W_hh1,
    const float* __restrict__ W_enc, const float* __restrict__ W_dec,
    const float* __restrict__ W_out, const float* __restrict__ embed,
    const float* __restrict__ hs_pad,
    const float* __restrict__ b_ih0, const float* __restrict__ b_hh0,
    const float* __restrict__ b_ih1, const float* __restrict__ b_hh1,
    const float* __restrict__ b_out,
    u16* __restrict__ Wih0b, u16* __restrict__ Whh0b,
    u16* __restrict__ Wih1b, u16* __restrict__ Whh1b,
    u16* __restrict__ Wencb, u16* __restrict__ Wdecb,
    u16* __restrict__ embedb, u16* __restrict__ hsb,
    u16* __restrict__ Wshufb,
    float* __restrict__ bsum0, float* __restrict__ bsum1, float* __restrict__ boutp)
{
  const int c1 = 1048576, c2 = 2097152, c3 = 3145728, c4 = 4194304;
  const int c5 = 4456448, c6 = 4718592, c7 = 5025792, c8 = 6664192;
  const int c9 = 6991872, c10 = 6993920, c11 = 6995968, c12 = 6996608;
  for (int i = blockIdx.x * blockDim.x + threadIdx.x; i < c12; i += gridDim.x * blockDim.x) {
    if (i < c1)       Wih0b[i]      = f2bf(W_ih0[i]);
    else if (i < c2)  Whh0b[i - c1] = f2bf(W_hh0[i - c1]);
    else if (i < c3)  Wih1b[i - c2] = f2bf(W_ih1[i - c2]);
    else if (i < c4)  Whh1b[i - c3] = f2bf(W_hh1[i - c3]);
    else if (i < c5)  Wencb[i - c4] = f2bf(W_enc[i - c4]);
    else if (i < c6)  Wdecb[i - c5] = f2bf(W_dec[i - c5]);
    else if (i < c7)  embedb[i - c6] = f2bf(embed[i - c6]);
    else if (i < c8)  hsb[i - c7]   = f2bf(hs_pad[i - c7]);
    else if (i < c9) {
      int e = i - c8;
      int kc = e / 10240, r = e % 10240;
      int tile = r >> 9, r2 = r & 511;
      int lane = r2 >> 3, ii = r2 & 7;
      int n = tile * 32 + (lane & 31);
      int k = kc * 16 + ((lane >> 5) << 3) + ii;
      Wshufb[e] = (n < 600) ? f2bf(W_out[n * 512 + k]) : (u16)0;
    }
    else if (i < c10) { int n = i - c9;  bsum0[n] = b_ih0[n] + b_hh0[n]; }
    else if (i < c11) { int n = i - c10; bsum1[n] = b_ih1[n] + b_hh1[n]; }
    else              { int n = i - c11; boutp[n] = (n < 600) ? b_out[n] : 0.0f; }
  }
}

// ------------------------------------------------- generic 64x64 MFMA GEMM
__global__ __launch_bounds__(256) void gemm_bf16(
    const u16* __restrict__ A, const u16* __restrict__ B,
    const int* __restrict__ ys, const float* __restrict__ bias,
    float* __restrict__ out, int N, int mode)
{
  int tid = threadIdx.x, wv = tid >> 6, l = tid & 63;
  int m0 = blockIdx.x * 64, n0 = blockIdx.y * 64;
  int row = m0 + wv * 16 + (l & 15);
  const u16* arow;
  if (mode == 1) { int uu = row >> 4, bb = row & 15; arow = A + (size_t)ys[bb * 64 + uu] * 512; }
  else           arow = A + (size_t)row * 512;
  int kof = (l >> 4) * 8;
  arow += kof;
  const u16* br = B + (size_t)(n0 + (l & 15)) * 512 + kof;
  f32x4 a0 = {0.f,0.f,0.f,0.f}, a1 = a0, a2 = a0, a3 = a0;
  for (int kk = 0; kk < 512; kk += 32) {
    short8 av = *(const short8*)(arow + kk);
    short8 b0 = *(const short8*)(br + kk);
    short8 b1 = *(const short8*)(br + 8192 + kk);
    short8 b2 = *(const short8*)(br + 16384 + kk);
    short8 b3 = *(const short8*)(br + 24576 + kk);
    a0 = __builtin_amdgcn_mfma_f32_16x16x32_bf16(av, b0, a0, 0, 0, 0);
    a1 = __builtin_amdgcn_mfma_f32_16x16x32_bf16(av, b1, a1, 0, 0, 0);
    a2 = __builtin_amdgcn_mfma_f32_16x16x32_bf16(av, b2, a2, 0, 0, 0);
    a3 = __builtin_amdgcn_mfma_f32_16x16x32_bf16(av, b3, a3, 0, 0, 0);
  }
  int col = l & 15, rb = m0 + wv * 16 + (l >> 4) * 4;
  f32x4 accs[4] = {a0, a1, a2, a3};
#pragma unroll
  for (int g = 0; g < 4; ++g) {
    int n = n0 + g * 16 + col;
    float bs = bias ? bias[n] : 0.0f;
#pragma unroll
    for (int i2 = 0; i2 < 4; ++i2)
      out[(size_t)(rb + i2) * N + n] = accs[g][i2] + bs;
  }
}

// ---------------------------------------------------------------- LSTM
// r11/r13 version (best measured ~190us): decoupled chains, flag arrays,
// coherent atomics, RELAXED polls + one acquire fence; producer vmcnt(0)+store.
#define L0WG 32
#define NWGT 96

DEVI short8 ald16(const u16* p) {
  union { unsigned long long q[2]; short8 v; } u;
  u.q[0] = __hip_atomic_load((unsigned long long*)p,       __ATOMIC_RELAXED, __HIP_MEMORY_SCOPE_AGENT);
  u.q[1] = __hip_atomic_load((unsigned long long*)(p + 4), __ATOMIC_RELAXED, __HIP_MEMORY_SCOPE_AGENT);
  return u.v;
}
DEVI void waitflags(const int* f0, const int* f1, int n0, int n1) {
  if (threadIdx.x < 64) {
    int l = threadIdx.x;
    for (;;) {
      int a = __hip_atomic_load((int*)(f0 + (l & 31) * 16), __ATOMIC_RELAXED, __HIP_MEMORY_SCOPE_AGENT);
      int b = __hip_atomic_load((int*)(f1 + l * 16),        __ATOMIC_RELAXED, __HIP_MEMORY_SCOPE_AGENT);
      if (__all(a >= n0 && b >= n1)) break;
      __builtin_amdgcn_s_sleep(1);
    }
    __builtin_amdgcn_fence(__ATOMIC_ACQUIRE, "agent");  // pin h-loads below poll
  }
  __syncthreads();
}
DEVI void postflag(int* slot, int val) {
  __syncthreads();
  if (threadIdx.x == 0) {
    asm volatile("s_waitcnt vmcnt(0)" ::: "memory");    // h-stores ack'd at L3
    __hip_atomic_store(slot, val, __ATOMIC_RELAXED, __HIP_MEMORY_SCOPE_AGENT);
  }
}
DEVI const u16* haddr(const u16* base, int slot, int k, int b) {
  return base + slot * 8192 + (k >> 4) * 256 + b * 16 + (k & 15);
}
DEVI void hstore(u16* base, int idx, u16 mine, int tid) {
  int other = __shfl_xor((int)mine, 1);
  if (!(tid & 1)) {
    uint32_t pkv = (uint32_t)mine | (((uint32_t)other & 0xffffu) << 16);
    __hip_atomic_store((uint32_t*)(base + idx), pkv, __ATOMIC_RELAXED, __HIP_MEMORY_SCOPE_AGENT);
  }
}

__global__ __launch_bounds__(256) void lstm_kernel(
    const float* __restrict__ Xg0,                 // [64][16][2048] (x@Wih0^T + bsum0)
    const u16* __restrict__ Whh0, const u16* __restrict__ Wih1, const u16* __restrict__ Whh1,
    const float* __restrict__ bsum1,
    u16* __restrict__ h0b, u16* __restrict__ h1b,  // [8][32][16][16] rings
    u16* __restrict__ Hdec,                        // [64][16][512] bf16
    int* __restrict__ flags0, int* __restrict__ flags1)
{
  __shared__ float red[16][256];
  const int bid = blockIdx.x, tid = threadIdx.x;
  const int wv = tid >> 6, l = tid & 63;
  const int lb = l & 15, kof = (l >> 4) * 8;
  const int drb = (l >> 4) * 4;

  if (bid < L0WG) {
    // ---------------- layer 0: units [16*bid, +16)
    const int be = tid >> 4, je = tid & 15, jg = (bid << 4) + je;
    short8 breg[16];
#pragma unroll
    for (int g = 0; g < 4; ++g) {
      const u16* bp = Whh0 + (size_t)(g * 512 + bid * 16 + lb) * 512 + wv * 128 + kof;
#pragma unroll
      for (int ks = 0; ks < 4; ++ks)
        breg[g * 4 + ks] = *(const short8*)(bp + ks * 32);
    }
    float c0 = 0.f;
    for (int t = 0; t < 64; ++t) {
      // prefetch Xg0 before the flag wait
      const float* xg = Xg0 + (size_t)((t << 4) + be) * 2048 + jg;
      float x0 = xg[0], x1 = xg[512], x2 = xg[1024], x3 = xg[1536];
      waitflags(flags0, flags1, t, (t > 7) ? (t - 7) : 0);
      const int rs = (t + 7) & 7;
      f32x4 g0 = {0.f,0.f,0.f,0.f}, g1 = g0, g2 = g0, g3 = g0;
#pragma unroll
      for (int ks = 0; ks < 4; ++ks) {
        int kk = wv * 128 + ks * 32 + kof;
        short8 av = ald16(haddr(h0b, rs, kk, lb));
        g0 = __builtin_amdgcn_mfma_f32_16x16x32_bf16(av, breg[0 * 4 + ks], g0, 0, 0, 0);
        g1 = __builtin_amdgcn_mfma_f32_16x16x32_bf16(av, breg[1 * 4 + ks], g1, 0, 0, 0);
        g2 = __builtin_amdgcn_mfma_f32_16x16x32_bf16(av, breg[2 * 4 + ks], g2, 0, 0, 0);
        g3 = __builtin_amdgcn_mfma_f32_16x16x32_bf16(av, breg[3 * 4 + ks], g3, 0, 0, 0);
      }
      f32x4 gs[4] = {g0, g1, g2, g3};
#pragma unroll
      for (int g = 0; g < 4; ++g)
#pragma unroll
        for (int i2 = 0; i2 < 4; ++i2)
          red[wv * 4 + g][(drb + i2) * 16 + lb] = gs[g][i2];
      __syncthreads();
      {
        float s0 = 0, s1 = 0, s2 = 0, s3 = 0;
#pragma unroll
        for (int v2 = 0; v2 < 4; ++v2) {
          s0 += red[v2 * 4 + 0][be * 16 + je]; s1 += red[v2 * 4 + 1][be * 16 + je];
          s2 += red[v2 * 4 + 2][be * 16 + je]; s3 += red[v2 * 4 + 3][be * 16 + je];
        }
        float gi = s0 + x0, gf = s1 + x1, gg = s2 + x2, go = s3 + x3;
        float I = sigm(gi), F = sigm(gf), G = tanh_c(gg), O = sigm(go);
        c0 = F * c0 + I * G;
        float h0 = O * tanh_c(c0);
        hstore(h0b, ((t & 7) * 32 + bid) * 256 + (tid & ~1), f2bf(h0), tid);
      }
      postflag(flags0 + bid * 16, t + 1);
    }
  } else {
    // ---------------- layer 1: units [8v, +8), v = bid-32
    const int v = bid - L0WG;
    const u16* base0 = (wv < 2) ? Wih1 : Whh1;
    const int kbase = (wv & 1) * 256;
    short8 breg[16];
#pragma unroll
    for (int tt = 0; tt < 2; ++tt) {
      int c = tt * 16 + lb, gate = c >> 3, du = c & 7;
      const u16* bp = base0 + (size_t)(gate * 512 + v * 8 + du) * 512 + kbase + kof;
#pragma unroll
      for (int ks = 0; ks < 8; ++ks)
        breg[tt * 8 + ks] = *(const short8*)(bp + ks * 32);
    }
    float bs0 = 0, bs1 = 0, bs2 = 0, bs3 = 0, c1 = 0.f;
    if (tid < 128) {
      int du = tid & 7, ju = v * 8 + du;
      bs0 = bsum1[ju]; bs1 = bsum1[512 + ju]; bs2 = bsum1[1024 + ju]; bs3 = bsum1[1536 + ju];
    }
    for (int t = 0; t < 64; ++t) {
      waitflags(flags0, flags1, t + 1, t);
      const u16* hsrc = (wv < 2) ? (h0b + (t & 7) * 8192) : (h1b + ((t + 7) & 7) * 8192);
      f32x4 g0 = {0.f,0.f,0.f,0.f}, g1 = g0;
#pragma unroll
      for (int ks = 0; ks < 8; ++ks) {
        int kk = kbase + ks * 32 + kof;
        short8 av = ald16(hsrc + (kk >> 4) * 256 + lb * 16 + (kk & 15));
        g0 = __builtin_amdgcn_mfma_f32_16x16x32_bf16(av, breg[0 * 8 + ks], g0, 0, 0, 0);
        g1 = __builtin_amdgcn_mfma_f32_16x16x32_bf16(av, breg[1 * 8 + ks], g1, 0, 0, 0);
      }
#pragma unroll
      for (int i2 = 0; i2 < 4; ++i2) {
        red[wv * 2 + 0][(drb + i2) * 16 + lb] = g0[i2];
        red[wv * 2 + 1][(drb + i2) * 16 + lb] = g1[i2];
      }
      __syncthreads();
      u16 hb = 0; int be = 0, ju = 0;
      if (tid < 128) {
        be = tid >> 3; int du = tid & 7; ju = v * 8 + du;
        float sg[4] = {bs0, bs1, bs2, bs3};
#pragma unroll
        for (int g = 0; g < 4; ++g) {
          int c = g * 8 + du, tt = c >> 4, cc = c & 15;
          float acc = 0.f;
#pragma unroll
          for (int w2 = 0; w2 < 4; ++w2) acc += red[w2 * 2 + tt][be * 16 + cc];
          sg[g] += acc;
        }
        float I = sigm(sg[0]), F = sigm(sg[1]), G = tanh_c(sg[2]), O = sigm(sg[3]);
        c1 = F * c1 + I * G;
        float h1v = O * tanh_c(c1);
        hb = f2bf(h1v);
        int idx = ((t & 7) * 32 + (ju >> 4)) * 256 + be * 16 + (ju & 15);
        hstore(h1b, idx & ~1, hb, tid);
      }
      postflag(flags1 + v * 16, t + 1);
      if (tid < 128) Hdec[(size_t)((t << 4) + be) * 512 + ju] = hb;  // off critical path
    }
  }
}

// ---------------------------------------------------------------- joint
// r13 joint (proven 297us): 256 thr (2Mx2N), M=64, N=320, W/z dbuf 48KB,
// prefetch distance 2, NT epilogue. NEW: bijective XCD swizzle (6400%8==0)
// so the 8 tiles sharing (b,tb) enc_p / (ub,b) dec_p panels land on one XCD L2.
__global__ __launch_bounds__(256) void joint_kernel(
    const float* __restrict__ enc_p,   // [16*200][512]
    const float* __restrict__ dec_p,   // [64*16][512]  row = u*16+b
    const u16* __restrict__ Wshuf,     // [32 kc][20 tile][64 lane][8] bf16
    const float* __restrict__ boutp,   // [640]
    float* __restrict__ out)
{
  __shared__ int4 wlds[2][1280];
  __shared__ int4 zlds[2][256];
  int bid = ((int)blockIdx.x & 7) * 800 + ((int)blockIdx.x >> 3);  // XCD swizzle
  int b = bid / 400, rem = bid % 400;
  int tb = rem / 8, rem2 = rem % 8;
  int ub = rem2 >> 1, nh = rem2 & 1;
  int tid = threadIdx.x, wv = tid >> 6, l = tid & 63;
  int mv = wv >> 1, nv = wv & 1;
  int ln31 = l & 31, lh = l >> 5;
  const int tile0 = nv * 5;
  f32x16 acc[5];
#pragma unroll
  for (int j = 0; j < 5; ++j) {
    float bv = boutp[nh * 320 + (tile0 + j) * 32 + ln31];
#pragma unroll
    for (int g = 0; g < 16; ++g) acc[j][g] = bv;
  }
  int zr = tid & 63, zg = tid >> 6;
  const float* er = enc_p + (size_t)(b * 200 + tb * 4 + (zr >> 4)) * 512 + zg * 8;
  const float* dr = dec_p + (size_t)((ub * 16 + (zr & 15)) * 16 + b) * 512 + zg * 8;
  const int zslot = ((zg >> 1) * 2 + (zr >> 5)) * 64 + ((zg & 1) << 5) + (zr & 31);
  const int4* gW = (const int4*)Wshuf;
  const int nhof = nh * 640;
  const int L0 = tid, L1 = 256 + tid, L2 = 512 + tid + ((tid >= 128) ? 640 : 0),
            L3 = 1408 + tid, L4 = 1664 + tid;
  const int S2 = 512 + tid;

  int4 aw0, aw1, aw2, aw3, aw4; float4 ae0, ae1, ad0, ad1;
  int4 bw0, bw1, bw2, bw3, bw4; float4 be0, be1, bd0, bd1;

  {
    int4 w0 = gW[nhof + L0], w1 = gW[nhof + L1], w2 = gW[nhof + L2],
         w3 = gW[nhof + L3], w4 = gW[nhof + L4];
    float4 e0 = *(const float4*)(er),     e1 = *(const float4*)(er + 4);
    float4 d0 = *(const float4*)(dr),     d1 = *(const float4*)(dr + 4);
    const int cb1 = 2560 + nhof;
    aw0 = gW[cb1 + L0]; aw1 = gW[cb1 + L1]; aw2 = gW[cb1 + L2];
    aw3 = gW[cb1 + L3]; aw4 = gW[cb1 + L4];
    ae0 = *(const float4*)(er + 32); ae1 = *(const float4*)(er + 36);
    ad0 = *(const float4*)(dr + 32); ad1 = *(const float4*)(dr + 36);
    int4 pk;
    pk.x = (int)tj2(e0.x + d0.x, e0.y + d0.y);
    pk.y = (int)tj2(e0.z + d0.z, e0.w + d0.w);
    pk.z = (int)tj2(e1.x + d1.x, e1.y + d1.y);
    pk.w = (int)tj2(e1.z + d1.z, e1.w + d1.w);
    zlds[0][zslot] = pk;
    wlds[0][tid] = w0; wlds[0][256 + tid] = w1; wlds[0][S2] = w2;
    wlds[0][768 + tid] = w3; wlds[0][1024 + tid] = w4;
    __syncthreads();
  }

#define JBODY(C, CUR, NXT, W0, W1, W2, W3, W4, E0, E1, D0, D1,                  \
              PW0, PW1, PW2, PW3, PW4, PE0, PE1, PD0, PD1)                      \
  {                                                                             \
    if ((C) + 2 <= 15) {                                                        \
      const int cb = ((C) + 2) * 2560 + nhof;                                   \
      PW0 = gW[cb + L0]; PW1 = gW[cb + L1]; PW2 = gW[cb + L2];                  \
      PW3 = gW[cb + L3]; PW4 = gW[cb + L4];                                     \
      int k0 = ((C) + 2) * 32;                                                  \
      PE0 = *(const float4*)(er + k0); PE1 = *(const float4*)(er + k0 + 4);     \
      PD0 = *(const float4*)(dr + k0); PD1 = *(const float4*)(dr + k0 + 4);     \
    }                                                                           \
    _Pragma("unroll")                                                           \
    for (int ks = 0; ks < 2; ++ks) {                                            \
      short8 aA = *(const short8*)&zlds[CUR][(ks * 2 + mv) * 64 + l];           \
      _Pragma("unroll")                                                         \
      for (int j = 0; j < 5; ++j) {                                             \
        short8 bw = *(const short8*)&wlds[CUR][ks * 640 + (tile0 + j) * 64 + l];\
        acc[j] = __builtin_amdgcn_mfma_f32_32x32x16_bf16(aA, bw, acc[j], 0, 0, 0); \
      }                                                                         \
    }                                                                           \
    if ((C) + 1 <= 15) {                                                        \
      wlds[NXT][tid] = W0; wlds[NXT][256 + tid] = W1; wlds[NXT][S2] = W2;       \
      wlds[NXT][768 + tid] = W3; wlds[NXT][1024 + tid] = W4;                    \
      int4 pk;                                                                  \
      pk.x = (int)tj2(E0.x + D0.x, E0.y + D0.y);                                \
      pk.y = (int)tj2(E0.z + D0.z, E0.w + D0.w);                                \
      pk.z = (int)tj2(E1.x + D1.x, E1.y + D1.y);                                \
      pk.w = (int)tj2(E1.z + D1.z, E1.w + D1.w);                                \
      zlds[NXT][zslot] = pk;                                                    \
    }                                                                           \
    __syncthreads();                                                            \
  }

  for (int cc = 0; cc < 8; ++cc) {
    const int c0 = cc * 2;
    JBODY(c0,     0, 1, aw0, aw1, aw2, aw3, aw4, ae0, ae1, ad0, ad1,
                        bw0, bw1, bw2, bw3, bw4, be0, be1, bd0, bd1);
    JBODY(c0 + 1, 1, 0, bw0, bw1, bw2, bw3, bw4, be0, be1, bd0, bd1,
                        aw0, aw1, aw2, aw3, aw4, ae0, ae1, ad0, ad1);
  }
#undef JBODY

#pragma unroll
  for (int j = 0; j < 5; ++j) {
    int n = nh * 320 + (tile0 + j) * 32 + ln31;
    if (n < 600) {
      int rbase = mv * 32 + 4 * lh;
#pragma unroll
      for (int g = 0; g < 16; ++g) {
        int r = rbase + (g & 3) + ((g >> 2) << 3);
        int tt = tb * 4 + (r >> 4), uu = ub * 16 + (r & 15);
        __builtin_nontemporal_store(
            acc[j][g], &out[(size_t)((b * 200 + tt) * 64 + uu) * 600 + n]);
      }
    }
  }
}

// ---------------------------------------------------------------- host
extern "C" void kernel_launch(void* const* d_in, const int* in_sizes, int n_in,
                              void* d_out, int out_size, void* d_ws, size_t ws_size,
                              hipStream_t stream) {
  const float* hs_pad = (const float*)d_in[0];
  const int*   ys     = (const int*)d_in[1];
  const float* embed  = (const float*)d_in[2];
  const float* W_ih0  = (const float*)d_in[3];
  const float* W_hh0  = (const float*)d_in[4];
  const float* b_ih0  = (const float*)d_in[5];
  const float* b_hh0  = (const float*)d_in[6];
  const float* W_ih1  = (const float*)d_in[7];
  const float* W_hh1  = (const float*)d_in[8];
  const float* b_ih1  = (const float*)d_in[9];
  const float* b_hh1  = (const float*)d_in[10];
  const float* W_enc  = (const float*)d_in[11];
  const float* b_enc  = (const float*)d_in[12];
  const float* W_dec  = (const float*)d_in[13];
  const float* W_out  = (const float*)d_in[14];
  const float* b_out  = (const float*)d_in[15];
  float* out = (float*)d_out;

  uint8_t* ws = (uint8_t*)d_ws;
  size_t off = 0;
  auto alloc = [&](size_t bytes) -> void* {
    void* p = ws + off;
    off = (off + bytes + 255) & ~(size_t)255;
    return p;
  };
  int* flags0   = (int*)alloc(2048);                     // 32 slots x 64B
  int* flags1   = (int*)alloc(4096);                     // 64 slots x 64B
  u16* h0buf    = (u16*)alloc(8 * 32 * 256 * 2);         // 128 KB ring
  u16* h1buf    = (u16*)alloc(8 * 32 * 256 * 2);         // 128 KB ring
  u16* Hdec     = (u16*)alloc(64 * 16 * 512 * 2);        // 1 MB
  float* Xg0    = (float*)alloc(1024 * 2048 * 4);        // 8 MB
  float* enc_p  = (float*)alloc(3200 * 512 * 4);         // 6.5 MB
  float* dec_p  = (float*)alloc(1024 * 512 * 4);         // 2 MB
  u16* Wih0b    = (u16*)alloc(2048 * 512 * 2);
  u16* Whh0b    = (u16*)alloc(2048 * 512 * 2);
  u16* Wih1b    = (u16*)alloc(2048 * 512 * 2);
  u16* Whh1b    = (u16*)alloc(2048 * 512 * 2);
  u16* Wencb    = (u16*)alloc(512 * 512 * 2);
  u16* Wdecb    = (u16*)alloc(512 * 512 * 2);
  u16* embedb   = (u16*)alloc(600 * 512 * 2);
  u16* hsb      = (u16*)alloc(3200 * 512 * 2);
  u16* Wshufb   = (u16*)alloc(32 * 20 * 64 * 8 * 2);
  float* bsum0  = (float*)alloc(2048 * 4);
  float* bsum1  = (float*)alloc(2048 * 4);
  float* boutp  = (float*)alloc(640 * 4);

  // zero flags + h rings (contiguous: 2048 + 4096 + 128K + 128K)
  (void)hipMemsetAsync(d_ws, 0, 2048 + 4096 + 131072 + 131072, stream);

  prep_kernel<<<2048, 256, 0, stream>>>(
      W_ih0, W_hh0, W_ih1, W_hh1, W_enc, W_dec, W_out, embed, hs_pad,
      b_ih0, b_hh0, b_ih1, b_hh1, b_out,
      Wih0b, Whh0b, Wih1b, Whh1b, Wencb, Wdecb, embedb, hsb, Wshufb,
      bsum0, bsum1, boutp);

  // Xg0 = embed[ys] @ W_ih0^T + (b_ih0 + b_hh0), rows m = u*16+b
  dim3 g1(16, 32);
  gemm_bf16<<<g1, 256, 0, stream>>>(embedb, Wih0b, ys, bsum0, Xg0, 2048, 1);
  // enc_p = hs @ W_enc^T + b_enc
  dim3 g2(50, 8);
  gemm_bf16<<<g2, 256, 0, stream>>>(hsb, Wencb, nullptr, b_enc, enc_p, 512, 0);
  // sequential 2-layer LSTM (r13 flag version, best measured)
  lstm_kernel<<<NWGT, 256, 0, stream>>>(Xg0, Whh0b, Wih1b, Whh1b, bsum1,
                                        h0buf, h1buf, Hdec, flags0, flags1);
  // dec_p = Hdec @ W_dec^T
  dim3 g3(16, 8);
  gemm_bf16<<<g3, 256, 0, stream>>>(Hdec, Wdecb, nullptr, nullptr, dec_p, 512, 0);
  // big fused joint (r13 + bijective XCD swizzle)
  joint_kernel<<<6400, 256, 0, stream>>>(enc_p, dec_p, Wshufb, boutp, out);
}

// Round 17
// 531.743 us; speedup vs baseline: 1.1755x; 1.0182x over previous
//
#include <hip/hip_runtime.h>
#include <hip/hip_bf16.h>
#include <stdint.h>

#define DEVI __device__ __forceinline__

typedef unsigned short u16;
typedef __attribute__((ext_vector_type(8))) short short8;
typedef __attribute__((ext_vector_type(4))) float f32x4;
typedef __attribute__((ext_vector_type(16))) float f32x16;

DEVI u16 f2bf(float f) {
  union { float f; uint32_t u; } v; v.f = f;
  return (u16)((v.u + 0x7fffu + ((v.u >> 16) & 1u)) >> 16);
}
DEVI float tanh_c(float x) {
  float e = __expf(x + x);
  float r = __builtin_amdgcn_rcpf(e + 1.0f);
  return __builtin_fmaf(-2.0f, r, 1.0f);
}
DEVI float sigm(float x) { return __builtin_amdgcn_rcpf(1.0f + __expf(-x)); }
DEVI uint32_t tj2(float a, float b) {
  float ea = __expf(a + a), eb = __expf(b + b);
  float ta = __builtin_fmaf(-2.0f, __builtin_amdgcn_rcpf(ea + 1.0f), 1.0f);
  float tb = __builtin_fmaf(-2.0f, __builtin_amdgcn_rcpf(eb + 1.0f), 1.0f);
  union { __hip_bfloat162 h; uint32_t u; } cv;
  cv.h = __float22bfloat162_rn(make_float2(ta, tb));
  return cv.u;
}

// ---------------------------------------------------------------- prep
// Vectorized: 4 elements per iteration (float4 load -> 2x u32 packed store).
// All region boundaries are multiples of 4. W_out-shuffle + bias tails scalar.
__global__ void prep_kernel(
    const float* __restrict__ W_ih0, const float* __restrict__ W_hh0,
    const float* __restrict__ W_ih1, const float* __restrict__ W_hh1,
    const float* __restrict__ W_enc, const float* __restrict__ W_dec,
    const float* __restrict__ W_out, const float* __restrict__ embed,
    const float* __restrict__ hs_pad,
    const float* __restrict__ b_ih0, const float* __restrict__ b_hh0,
    const float* __restrict__ b_ih1, const float* __restrict__ b_hh1,
    const float* __restrict__ b_out,
    u16* __restrict__ Wih0b, u16* __restrict__ Whh0b,
    u16* __restrict__ Wih1b, u16* __restrict__ Whh1b,
    u16* __restrict__ Wencb, u16* __restrict__ Wdecb,
    u16* __restrict__ embedb, u16* __restrict__ hsb,
    u16* __restrict__ Wshufb,
    float* __restrict__ bsum0, float* __restrict__ bsum1, float* __restrict__ boutp)
{
  const int c1 = 1048576, c2 = 2097152, c3 = 3145728, c4 = 4194304;
  const int c5 = 4456448, c6 = 4718592, c7 = 5025792, c8 = 6664192;
  const int c9 = 6991872, c10 = 6993920, c11 = 6995968, c12 = 6996608;
  const int v8 = c8 >> 2;                 // 1,666,048 vector iterations
  const int total = v8 + (c12 - c8);      // + 332,416 scalar
  for (int i = blockIdx.x * blockDim.x + threadIdx.x; i < total; i += gridDim.x * blockDim.x) {
    if (i < v8) {
      int e4 = i << 2;
      const float* src; u16* dst; int off;
      if (e4 < c1)      { src = W_ih0;  dst = Wih0b;  off = e4; }
      else if (e4 < c2) { src = W_hh0;  dst = Whh0b;  off = e4 - c1; }
      else if (e4 < c3) { src = W_ih1;  dst = Wih1b;  off = e4 - c2; }
      else if (e4 < c4) { src = W_hh1;  dst = Whh1b;  off = e4 - c3; }
      else if (e4 < c5) { src = W_enc;  dst = Wencb;  off = e4 - c4; }
      else if (e4 < c6) { src = W_dec;  dst = Wdecb;  off = e4 - c5; }
      else if (e4 < c7) { src = embed;  dst = embedb; off = e4 - c6; }
      else              { src = hs_pad; dst = hsb;    off = e4 - c7; }
      float4 v = *(const float4*)(src + off);
      uint2 pk;
      pk.x = (uint32_t)f2bf(v.x) | ((uint32_t)f2bf(v.y) << 16);
      pk.y = (uint32_t)f2bf(v.z) | ((uint32_t)f2bf(v.w) << 16);
      *(uint2*)(dst + off) = pk;
    } else {
      int e = i - v8 + c8;
      if (e < c9) {
        // W_out pre-shuffled for 32x32x16 B-fragments: [32 kc][20 tile][64 lane][8]
        int x = e - c8;
        int kc = x / 10240, r = x % 10240;
        int tile = r >> 9, r2 = r & 511;
        int lane = r2 >> 3, ii = r2 & 7;
        int n = tile * 32 + (lane & 31);
        int k = kc * 16 + ((lane >> 5) << 3) + ii;
        Wshufb[x] = (n < 600) ? f2bf(W_out[n * 512 + k]) : (u16)0;
      }
      else if (e < c10) { int n = e - c9;  bsum0[n] = b_ih0[n] + b_hh0[n]; }
      else if (e < c11) { int n = e - c10; bsum1[n] = b_ih1[n] + b_hh1[n]; }
      else              { int n = e - c11; boutp[n] = (n < 600) ? b_out[n] : 0.0f; }
    }
  }
}

// ---------------------------------------------- 64x64 MFMA GEMM tile (device)
template<int MODE>
DEVI void gemm_tile(const u16* __restrict__ A, const u16* __restrict__ B,
                    const int* __restrict__ ys, const float* __restrict__ bias,
                    float* __restrict__ out, int N, int m0, int n0, int tid)
{
  int wv = tid >> 6, l = tid & 63;
  int row = m0 + wv * 16 + (l & 15);
  const u16* arow;
  if (MODE == 1) { int uu = row >> 4, bb = row & 15; arow = A + (size_t)ys[bb * 64 + uu] * 512; }
  else           arow = A + (size_t)row * 512;
  int kof = (l >> 4) * 8;
  arow += kof;
  const u16* br = B + (size_t)(n0 + (l & 15)) * 512 + kof;
  f32x4 a0 = {0.f,0.f,0.f,0.f}, a1 = a0, a2 = a0, a3 = a0;
  for (int kk = 0; kk < 512; kk += 32) {
    short8 av = *(const short8*)(arow + kk);
    short8 b0 = *(const short8*)(br + kk);
    short8 b1 = *(const short8*)(br + 8192 + kk);
    short8 b2 = *(const short8*)(br + 16384 + kk);
    short8 b3 = *(const short8*)(br + 24576 + kk);
    a0 = __builtin_amdgcn_mfma_f32_16x16x32_bf16(av, b0, a0, 0, 0, 0);
    a1 = __builtin_amdgcn_mfma_f32_16x16x32_bf16(av, b1, a1, 0, 0, 0);
    a2 = __builtin_amdgcn_mfma_f32_16x16x32_bf16(av, b2, a2, 0, 0, 0);
    a3 = __builtin_amdgcn_mfma_f32_16x16x32_bf16(av, b3, a3, 0, 0, 0);
  }
  int col = l & 15, rb = m0 + wv * 16 + (l >> 4) * 4;
  f32x4 accs[4] = {a0, a1, a2, a3};
#pragma unroll
  for (int g = 0; g < 4; ++g) {
    int n = n0 + g * 16 + col;
    float bs = bias ? bias[n] : 0.0f;
#pragma unroll
    for (int i2 = 0; i2 < 4; ++i2)
      out[(size_t)(rb + i2) * N + n] = accs[g][i2] + bs;
  }
}

// --------------------------------------------- pre-GEMMs: Xg0 + enc_p (merged)
__global__ __launch_bounds__(256) void gemm_pre(
    const u16* __restrict__ embedb, const u16* __restrict__ Wih0b,
    const int* __restrict__ ys, const float* __restrict__ bsum0,
    float* __restrict__ Xg0,
    const u16* __restrict__ hsb, const u16* __restrict__ Wencb,
    const float* __restrict__ b_enc, float* __restrict__ enc_p)
{
  int bid = blockIdx.x, tid = threadIdx.x;
  if (bid < 512) {
    int mt = bid >> 5, nt = bid & 31;
    gemm_tile<1>(embedb, Wih0b, ys, bsum0, Xg0, 2048, mt * 64, nt * 64, tid);
  } else {
    int g = bid - 512, mt = g >> 3, nt = g & 7;
    gemm_tile<0>(hsb, Wencb, nullptr, b_enc, enc_p, 512, mt * 64, nt * 64, tid);
  }
}

// ----------------------------------------------- dec_p GEMM (after LSTM)
__global__ __launch_bounds__(256) void gemm_dec(
    const u16* __restrict__ Hdec, const u16* __restrict__ Wdecb,
    float* __restrict__ dec_p)
{
  int mt = blockIdx.x >> 3, nt = blockIdx.x & 7;
  gemm_tile<0>(Hdec, Wdecb, nullptr, nullptr, dec_p, 512,
               mt * 64, nt * 64, threadIdx.x);
}

// ---------------------------------------------------------------- LSTM
// r13/r16 version (best measured): decoupled chains, flag arrays, coherent
// atomics, RELAXED polls + one acquire fence; producer vmcnt(0)+relaxed store.
#define L0WG 32
#define NWGT 96

DEVI short8 ald16(const u16* p) {
  union { unsigned long long q[2]; short8 v; } u;
  u.q[0] = __hip_atomic_load((unsigned long long*)p,       __ATOMIC_RELAXED, __HIP_MEMORY_SCOPE_AGENT);
  u.q[1] = __hip_atomic_load((unsigned long long*)(p + 4), __ATOMIC_RELAXED, __HIP_MEMORY_SCOPE_AGENT);
  return u.v;
}
DEVI void waitflags(const int* f0, const int* f1, int n0, int n1) {
  if (threadIdx.x < 64) {
    int l = threadIdx.x;
    for (;;) {
      int a = __hip_atomic_load((int*)(f0 + (l & 31) * 16), __ATOMIC_RELAXED, __HIP_MEMORY_SCOPE_AGENT);
      int b = __hip_atomic_load((int*)(f1 + l * 16),        __ATOMIC_RELAXED, __HIP_MEMORY_SCOPE_AGENT);
      if (__all(a >= n0 && b >= n1)) break;
      __builtin_amdgcn_s_sleep(1);
    }
    __builtin_amdgcn_fence(__ATOMIC_ACQUIRE, "agent");  // pin h-loads below poll
  }
  __syncthreads();
}
DEVI void postflag(int* slot, int val) {
  __syncthreads();
  if (threadIdx.x == 0) {
    asm volatile("s_waitcnt vmcnt(0)" ::: "memory");    // h-stores ack'd at L3
    __hip_atomic_store(slot, val, __ATOMIC_RELAXED, __HIP_MEMORY_SCOPE_AGENT);
  }
}
DEVI const u16* haddr(const u16* base, int slot, int k, int b) {
  return base + slot * 8192 + (k >> 4) * 256 + b * 16 + (k & 15);
}
DEVI void hstore(u16* base, int idx, u16 mine, int tid) {
  int other = __shfl_xor((int)mine, 1);
  if (!(tid & 1)) {
    uint32_t pkv = (uint32_t)mine | (((uint32_t)other & 0xffffu) << 16);
    __hip_atomic_store((uint32_t*)(base + idx), pkv, __ATOMIC_RELAXED, __HIP_MEMORY_SCOPE_AGENT);
  }
}

__global__ __launch_bounds__(256) void lstm_kernel(
    const float* __restrict__ Xg0,                 // [64][16][2048] (x@Wih0^T + bsum0)
    const u16* __restrict__ Whh0, const u16* __restrict__ Wih1, const u16* __restrict__ Whh1,
    const float* __restrict__ bsum1,
    u16* __restrict__ h0b, u16* __restrict__ h1b,  // [8][32][16][16] rings
    u16* __restrict__ Hdec,                        // [64][16][512] bf16
    int* __restrict__ flags0, int* __restrict__ flags1)
{
  __shared__ float red[16][256];
  const int bid = blockIdx.x, tid = threadIdx.x;
  const int wv = tid >> 6, l = tid & 63;
  const int lb = l & 15, kof = (l >> 4) * 8;
  const int drb = (l >> 4) * 4;

  if (bid < L0WG) {
    // ---------------- layer 0: units [16*bid, +16)
    const int be = tid >> 4, je = tid & 15, jg = (bid << 4) + je;
    short8 breg[16];
#pragma unroll
    for (int g = 0; g < 4; ++g) {
      const u16* bp = Whh0 + (size_t)(g * 512 + bid * 16 + lb) * 512 + wv * 128 + kof;
#pragma unroll
      for (int ks = 0; ks < 4; ++ks)
        breg[g * 4 + ks] = *(const short8*)(bp + ks * 32);
    }
    float c0 = 0.f;
    for (int t = 0; t < 64; ++t) {
      // prefetch Xg0 before the flag wait
      const float* xg = Xg0 + (size_t)((t << 4) + be) * 2048 + jg;
      float x0 = xg[0], x1 = xg[512], x2 = xg[1024], x3 = xg[1536];
      waitflags(flags0, flags1, t, (t > 7) ? (t - 7) : 0);
      const int rs = (t + 7) & 7;
      f32x4 g0 = {0.f,0.f,0.f,0.f}, g1 = g0, g2 = g0, g3 = g0;
#pragma unroll
      for (int ks = 0; ks < 4; ++ks) {
        int kk = wv * 128 + ks * 32 + kof;
        short8 av = ald16(haddr(h0b, rs, kk, lb));
        g0 = __builtin_amdgcn_mfma_f32_16x16x32_bf16(av, breg[0 * 4 + ks], g0, 0, 0, 0);
        g1 = __builtin_amdgcn_mfma_f32_16x16x32_bf16(av, breg[1 * 4 + ks], g1, 0, 0, 0);
        g2 = __builtin_amdgcn_mfma_f32_16x16x32_bf16(av, breg[2 * 4 + ks], g2, 0, 0, 0);
        g3 = __builtin_amdgcn_mfma_f32_16x16x32_bf16(av, breg[3 * 4 + ks], g3, 0, 0, 0);
      }
      f32x4 gs[4] = {g0, g1, g2, g3};
#pragma unroll
      for (int g = 0; g < 4; ++g)
#pragma unroll
        for (int i2 = 0; i2 < 4; ++i2)
          red[wv * 4 + g][(drb + i2) * 16 + lb] = gs[g][i2];
      __syncthreads();
      {
        float s0 = 0, s1 = 0, s2 = 0, s3 = 0;
#pragma unroll
        for (int v2 = 0; v2 < 4; ++v2) {
          s0 += red[v2 * 4 + 0][be * 16 + je]; s1 += red[v2 * 4 + 1][be * 16 + je];
          s2 += red[v2 * 4 + 2][be * 16 + je]; s3 += red[v2 * 4 + 3][be * 16 + je];
        }
        float gi = s0 + x0, gf = s1 + x1, gg = s2 + x2, go = s3 + x3;
        float I = sigm(gi), F = sigm(gf), G = tanh_c(gg), O = sigm(go);
        c0 = F * c0 + I * G;
        float h0 = O * tanh_c(c0);
        hstore(h0b, ((t & 7) * 32 + bid) * 256 + (tid & ~1), f2bf(h0), tid);
      }
      postflag(flags0 + bid * 16, t + 1);
    }
  } else {
    // ---------------- layer 1: units [8v, +8), v = bid-32
    const int v = bid - L0WG;
    const u16* base0 = (wv < 2) ? Wih1 : Whh1;
    const int kbase = (wv & 1) * 256;
    short8 breg[16];
#pragma unroll
    for (int tt = 0; tt < 2; ++tt) {
      int c = tt * 16 + lb, gate = c >> 3, du = c & 7;
      const u16* bp = base0 + (size_t)(gate * 512 + v * 8 + du) * 512 + kbase + kof;
#pragma unroll
      for (int ks = 0; ks < 8; ++ks)
        breg[tt * 8 + ks] = *(const short8*)(bp + ks * 32);
    }
    float bs0 = 0, bs1 = 0, bs2 = 0, bs3 = 0, c1 = 0.f;
    if (tid < 128) {
      int du = tid & 7, ju = v * 8 + du;
      bs0 = bsum1[ju]; bs1 = bsum1[512 + ju]; bs2 = bsum1[1024 + ju]; bs3 = bsum1[1536 + ju];
    }
    for (int t = 0; t < 64; ++t) {
      waitflags(flags0, flags1, t + 1, t);
      const u16* hsrc = (wv < 2) ? (h0b + (t & 7) * 8192) : (h1b + ((t + 7) & 7) * 8192);
      f32x4 g0 = {0.f,0.f,0.f,0.f}, g1 = g0;
#pragma unroll
      for (int ks = 0; ks < 8; ++ks) {
        int kk = kbase + ks * 32 + kof;
        short8 av = ald16(hsrc + (kk >> 4) * 256 + lb * 16 + (kk & 15));
        g0 = __builtin_amdgcn_mfma_f32_16x16x32_bf16(av, breg[0 * 8 + ks], g0, 0, 0, 0);
        g1 = __builtin_amdgcn_mfma_f32_16x16x32_bf16(av, breg[1 * 8 + ks], g1, 0, 0, 0);
      }
#pragma unroll
      for (int i2 = 0; i2 < 4; ++i2) {
        red[wv * 2 + 0][(drb + i2) * 16 + lb] = g0[i2];
        red[wv * 2 + 1][(drb + i2) * 16 + lb] = g1[i2];
      }
      __syncthreads();
      u16 hb = 0; int be = 0, ju = 0;
      if (tid < 128) {
        be = tid >> 3; int du = tid & 7; ju = v * 8 + du;
        float sg[4] = {bs0, bs1, bs2, bs3};
#pragma unroll
        for (int g = 0; g < 4; ++g) {
          int c = g * 8 + du, tt = c >> 4, cc = c & 15;
          float acc = 0.f;
#pragma unroll
          for (int w2 = 0; w2 < 4; ++w2) acc += red[w2 * 2 + tt][be * 16 + cc];
          sg[g] += acc;
        }
        float I = sigm(sg[0]), F = sigm(sg[1]), G = tanh_c(sg[2]), O = sigm(sg[3]);
        c1 = F * c1 + I * G;
        float h1v = O * tanh_c(c1);
        hb = f2bf(h1v);
        int idx = ((t & 7) * 32 + (ju >> 4)) * 256 + be * 16 + (ju & 15);
        hstore(h1b, idx & ~1, hb, tid);
      }
      postflag(flags1 + v * 16, t + 1);
      if (tid < 128) Hdec[(size_t)((t << 4) + be) * 512 + ju] = hb;  // off critical path
    }
  }
}

// ---------------------------------------------------------------- joint
// r16 joint (proven ~290us): 256 thr (2Mx2N), M=64, N=320, W/z dbuf 48KB,
// prefetch distance 2, NT epilogue, bijective XCD swizzle.
__global__ __launch_bounds__(256) void joint_kernel(
    const float* __restrict__ enc_p,   // [16*200][512]
    const float* __restrict__ dec_p,   // [64*16][512]  row = u*16+b
    const u16* __restrict__ Wshuf,     // [32 kc][20 tile][64 lane][8] bf16
    const float* __restrict__ boutp,   // [640]
    float* __restrict__ out)
{
  __shared__ int4 wlds[2][1280];
  __shared__ int4 zlds[2][256];
  int bid = ((int)blockIdx.x & 7) * 800 + ((int)blockIdx.x >> 3);  // XCD swizzle
  int b = bid / 400, rem = bid % 400;
  int tb = rem / 8, rem2 = rem % 8;
  int ub = rem2 >> 1, nh = rem2 & 1;
  int tid = threadIdx.x, wv = tid >> 6, l = tid & 63;
  int mv = wv >> 1, nv = wv & 1;
  int ln31 = l & 31, lh = l >> 5;
  const int tile0 = nv * 5;
  f32x16 acc[5];
#pragma unroll
  for (int j = 0; j < 5; ++j) {
    float bv = boutp[nh * 320 + (tile0 + j) * 32 + ln31];
#pragma unroll
    for (int g = 0; g < 16; ++g) acc[j][g] = bv;
  }
  int zr = tid & 63, zg = tid >> 6;
  const float* er = enc_p + (size_t)(b * 200 + tb * 4 + (zr >> 4)) * 512 + zg * 8;
  const float* dr = dec_p + (size_t)((ub * 16 + (zr & 15)) * 16 + b) * 512 + zg * 8;
  const int zslot = ((zg >> 1) * 2 + (zr >> 5)) * 64 + ((zg & 1) << 5) + (zr & 31);
  const int4* gW = (const int4*)Wshuf;
  const int nhof = nh * 640;
  const int L0 = tid, L1 = 256 + tid, L2 = 512 + tid + ((tid >= 128) ? 640 : 0),
            L3 = 1408 + tid, L4 = 1664 + tid;
  const int S2 = 512 + tid;

  int4 aw0, aw1, aw2, aw3, aw4; float4 ae0, ae1, ad0, ad1;
  int4 bw0, bw1, bw2, bw3, bw4; float4 be0, be1, bd0, bd1;

  {
    int4 w0 = gW[nhof + L0], w1 = gW[nhof + L1], w2 = gW[nhof + L2],
         w3 = gW[nhof + L3], w4 = gW[nhof + L4];
    float4 e0 = *(const float4*)(er),     e1 = *(const float4*)(er + 4);
    float4 d0 = *(const float4*)(dr),     d1 = *(const float4*)(dr + 4);
    const int cb1 = 2560 + nhof;
    aw0 = gW[cb1 + L0]; aw1 = gW[cb1 + L1]; aw2 = gW[cb1 + L2];
    aw3 = gW[cb1 + L3]; aw4 = gW[cb1 + L4];
    ae0 = *(const float4*)(er + 32); ae1 = *(const float4*)(er + 36);
    ad0 = *(const float4*)(dr + 32); ad1 = *(const float4*)(dr + 36);
    int4 pk;
    pk.x = (int)tj2(e0.x + d0.x, e0.y + d0.y);
    pk.y = (int)tj2(e0.z + d0.z, e0.w + d0.w);
    pk.z = (int)tj2(e1.x + d1.x, e1.y + d1.y);
    pk.w = (int)tj2(e1.z + d1.z, e1.w + d1.w);
    zlds[0][zslot] = pk;
    wlds[0][tid] = w0; wlds[0][256 + tid] = w1; wlds[0][S2] = w2;
    wlds[0][768 + tid] = w3; wlds[0][1024 + tid] = w4;
    __syncthreads();
  }

#define JBODY(C, CUR, NXT, W0, W1, W2, W3, W4, E0, E1, D0, D1,                  \
              PW0, PW1, PW2, PW3, PW4, PE0, PE1, PD0, PD1)                      \
  {                                                                             \
    if ((C) + 2 <= 15) {                                                        \
      const int cb = ((C) + 2) * 2560 + nhof;                                   \
      PW0 = gW[cb + L0]; PW1 = gW[cb + L1]; PW2 = gW[cb + L2];                  \
      PW3 = gW[cb + L3]; PW4 = gW[cb + L4];                                     \
      int k0 = ((C) + 2) * 32;                                                  \
      PE0 = *(const float4*)(er + k0); PE1 = *(const float4*)(er + k0 + 4);     \
      PD0 = *(const float4*)(dr + k0); PD1 = *(const float4*)(dr + k0 + 4);     \
    }                                                                           \
    _Pragma("unroll")                                                           \
    for (int ks = 0; ks < 2; ++ks) {                                            \
      short8 aA = *(const short8*)&zlds[CUR][(ks * 2 + mv) * 64 + l];           \
      _Pragma("unroll")                                                         \
      for (int j = 0; j < 5; ++j) {                                             \
        short8 bw = *(const short8*)&wlds[CUR][ks * 640 + (tile0 + j) * 64 + l];\
        acc[j] = __builtin_amdgcn_mfma_f32_32x32x16_bf16(aA, bw, acc[j], 0, 0, 0); \
      }                                                                         \
    }                                                                           \
    if ((C) + 1 <= 15) {                                                        \
      wlds[NXT][tid] = W0; wlds[NXT][256 + tid] = W1; wlds[NXT][S2] = W2;       \
      wlds[NXT][768 + tid] = W3; wlds[NXT][1024 + tid] = W4;                    \
      int4 pk;                                                                  \
      pk.x = (int)tj2(E0.x + D0.x, E0.y + D0.y);                                \
      pk.y = (int)tj2(E0.z + D0.z, E0.w + D0.w);                                \
      pk.z = (int)tj2(E1.x + D1.x, E1.y + D1.y);                                \
      pk.w = (int)tj2(E1.z + D1.z, E1.w + D1.w);                                \
      zlds[NXT][zslot] = pk;                                                    \
    }                                                                           \
    __syncthreads();                                                            \
  }

  for (int cc = 0; cc < 8; ++cc) {
    const int c0 = cc * 2;
    JBODY(c0,     0, 1, aw0, aw1, aw2, aw3, aw4, ae0, ae1, ad0, ad1,
                        bw0, bw1, bw2, bw3, bw4, be0, be1, bd0, bd1);
    JBODY(c0 + 1, 1, 0, bw0, bw1, bw2, bw3, bw4, be0, be1, bd0, bd1,
                        aw0, aw1, aw2, aw3, aw4, ae0, ae1, ad0, ad1);
  }
#undef JBODY

#pragma unroll
  for (int j = 0; j < 5; ++j) {
    int n = nh * 320 + (tile0 + j) * 32 + ln31;
    if (n < 600) {
      int rbase = mv * 32 + 4 * lh;
#pragma unroll
      for (int g = 0; g < 16; ++g) {
        int r = rbase + (g & 3) + ((g >> 2) << 3);
        int tt = tb * 4 + (r >> 4), uu = ub * 16 + (r & 15);
        __builtin_nontemporal_store(
            acc[j][g], &out[(size_t)((b * 200 + tt) * 64 + uu) * 600 + n]);
      }
    }
  }
}

// ---------------------------------------------------------------- host
extern "C" void kernel_launch(void* const* d_in, const int* in_sizes, int n_in,
                              void* d_out, int out_size, void* d_ws, size_t ws_size,
                              hipStream_t stream) {
  const float* hs_pad = (const float*)d_in[0];
  const int*   ys     = (const int*)d_in[1];
  const float* embed  = (const float*)d_in[2];
  const float* W_ih0  = (const float*)d_in[3];
  const float* W_hh0  = (const float*)d_in[4];
  const float* b_ih0  = (const float*)d_in[5];
  const float* b_hh0  = (const float*)d_in[6];
  const float* W_ih1  = (const float*)d_in[7];
  const float* W_hh1  = (const float*)d_in[8];
  const float* b_ih1  = (const float*)d_in[9];
  const float* b_hh1  = (const float*)d_in[10];
  const float* W_enc  = (const float*)d_in[11];
  const float* b_enc  = (const float*)d_in[12];
  const float* W_dec  = (const float*)d_in[13];
  const float* W_out  = (const float*)d_in[14];
  const float* b_out  = (const float*)d_in[15];
  float* out = (float*)d_out;

  uint8_t* ws = (uint8_t*)d_ws;
  size_t off = 0;
  auto alloc = [&](size_t bytes) -> void* {
    void* p = ws + off;
    off = (off + bytes + 255) & ~(size_t)255;
    return p;
  };
  int* flags0   = (int*)alloc(2048);                     // 32 slots x 64B
  int* flags1   = (int*)alloc(4096);                     // 64 slots x 64B
  u16* h0buf    = (u16*)alloc(8 * 32 * 256 * 2);         // 128 KB ring
  u16* h1buf    = (u16*)alloc(8 * 32 * 256 * 2);         // 128 KB ring
  u16* Hdec     = (u16*)alloc(64 * 16 * 512 * 2);        // 1 MB
  float* Xg0    = (float*)alloc(1024 * 2048 * 4);        // 8 MB
  float* enc_p  = (float*)alloc(3200 * 512 * 4);         // 6.5 MB
  float* dec_p  = (float*)alloc(1024 * 512 * 4);         // 2 MB
  u16* Wih0b    = (u16*)alloc(2048 * 512 * 2);
  u16* Whh0b    = (u16*)alloc(2048 * 512 * 2);
  u16* Wih1b    = (u16*)alloc(2048 * 512 * 2);
  u16* Whh1b    = (u16*)alloc(2048 * 512 * 2);
  u16* Wencb    = (u16*)alloc(512 * 512 * 2);
  u16* Wdecb    = (u16*)alloc(512 * 512 * 2);
  u16* embedb   = (u16*)alloc(600 * 512 * 2);
  u16* hsb      = (u16*)alloc(3200 * 512 * 2);
  u16* Wshufb   = (u16*)alloc(32 * 20 * 64 * 8 * 2);
  float* bsum0  = (float*)alloc(2048 * 4);
  float* bsum1  = (float*)alloc(2048 * 4);
  float* boutp  = (float*)alloc(640 * 4);

  // zero flags + h rings (contiguous: 2048 + 4096 + 128K + 128K)
  (void)hipMemsetAsync(d_ws, 0, 2048 + 4096 + 131072 + 131072, stream);

  prep_kernel<<<2048, 256, 0, stream>>>(
      W_ih0, W_hh0, W_ih1, W_hh1, W_enc, W_dec, W_out, embed, hs_pad,
      b_ih0, b_hh0, b_ih1, b_hh1, b_out,
      Wih0b, Whh0b, Wih1b, Whh1b, Wencb, Wdecb, embedb, hsb, Wshufb,
      bsum0, bsum1, boutp);

  // Xg0 + enc_p merged (both plain; LSTM inputs fully materialized)
  gemm_pre<<<912, 256, 0, stream>>>(embedb, Wih0b, ys, bsum0, Xg0,
                                    hsb, Wencb, b_enc, enc_p);

  // sequential 2-layer LSTM (r13 flag version, best measured)
  lstm_kernel<<<NWGT, 256, 0, stream>>>(Xg0, Whh0b, Wih1b, Whh1b, bsum1,
                                        h0buf, h1buf, Hdec, flags0, flags1);
  // dec_p = Hdec @ W_dec^T
  gemm_dec<<<128, 256, 0, stream>>>(Hdec, Wdecb, dec_p);
  // big fused joint (r16: prefetch-2 + NT epilogue + XCD swizzle)
  joint_kernel<<<6400, 256, 0, stream>>>(enc_p, dec_p, Wshufb, boutp, out);
}